// Round 10
// baseline (544.932 us; speedup 1.0000x reference)
//
#include <hip/hip_runtime.h>
#include <hip/hip_bf16.h>
#include <math.h>

// GAE on MI355X. N=16384 nodes, E=524288 edges.
// R10: adj path occupancy 2 -> 4 blocks/CU: per-ks fragment staging (~115
// VGPR, launch_bounds cap 128) + chunked 32-row LDS staging (16.9 KB).
// Same 128x128 tile, identical math. Rest identical to R9.

constexpr int kN = 16384;
constexpr int kE = 524288;
constexpr float kEps = 1e-5f;

typedef __attribute__((ext_vector_type(8))) short short8v;   // 8 x bf16
typedef __attribute__((ext_vector_type(4))) float f32x4;

__device__ inline float bf2f(unsigned short u) {
  return __uint_as_float(((unsigned)u) << 16);
}
__device__ inline unsigned short f2bf(float f) {  // RNE
  unsigned u = __float_as_uint(f);
  return (unsigned short)((u + 0x7fff + ((u >> 16) & 1)) >> 16);
}

// ---------------------------------------------------------------- utility
__global__ void zero_kernel(int* counts, float* sums1, float* sums2,
                            const float* __restrict__ we, __hip_bfloat16* wfr) {
  int i = blockIdx.x * 256 + threadIdx.x;
  if (i < kN) counts[i] = 0;
  if (i < 256) sums1[i] = 0.f;
  if (i < 128) sums2[i] = 0.f;
  if (i < 2048) {
    int f = i >> 9, l = (i >> 3) & 63, j = i & 7;
    int lr = l & 15, lg = l >> 4;
    int krow = f * 32 + lg * 8 + j;
    wfr[i] = __float2bfloat16(we[krow * 16 + lr]);
  }
}

__global__ void hist_kernel(const int* __restrict__ dst, int* __restrict__ counts) {
  int e = blockIdx.x * 256 + threadIdx.x;
  if (e < kE) atomicAdd(&counts[dst[e]], 1);
}

__global__ __launch_bounds__(1024) void scan_kernel(const int* __restrict__ counts,
    int* __restrict__ offsets, int* __restrict__ pos, float* __restrict__ dis) {
  __shared__ int wave_tot[16];
  int tid = threadIdx.x;
  int base = tid * 16;
  int loc[16];
  int s = 0;
#pragma unroll
  for (int i = 0; i < 16; i++) { loc[i] = s; s += counts[base + i]; }
  int lane = tid & 63, wv = tid >> 6;
  int incl = s;
#pragma unroll
  for (int d = 1; d < 64; d <<= 1) {
    int v = __shfl_up(incl, d, 64);
    if (lane >= d) incl += v;
  }
  if (lane == 63) wave_tot[wv] = incl;
  __syncthreads();
  int woff = 0;
  for (int i = 0; i < wv; i++) woff += wave_tot[i];
  int excl = woff + incl - s;
#pragma unroll
  for (int i = 0; i < 16; i++) {
    int o = excl + loc[i];
    offsets[base + i] = o;
    pos[base + i] = o;
    dis[base + i] = rsqrtf((float)counts[base + i] + 1.0f);  // +1 self-loop
  }
}

__global__ void fill_kernel(const int* __restrict__ src, const int* __restrict__ dst,
                            int* __restrict__ pos, int* __restrict__ csr_src) {
  int e = blockIdx.x * 256 + threadIdx.x;
  if (e < kE) {
    int d = dst[e];
    int p = atomicAdd(&pos[d], 1);
    csr_src[p] = src[e];
  }
}

// ---------------------------------------------------------------- GEMM layer 1
__global__ __launch_bounds__(256) void gemm1_kernel(
    const float* __restrict__ A, const float* __restrict__ W,
    const float* __restrict__ dis, __hip_bfloat16* __restrict__ out) {
  constexpr int BC = 128, NJ = 8, WF4 = 4;
  __shared__ float xs[64 * 33];
  __shared__ float wsh[32 * BC];
  int tid = threadIdx.x;
  int tx = tid & 15, ty = tid >> 4;
  int r0 = blockIdx.x * 64;
  float acc[4][NJ];
#pragma unroll
  for (int r = 0; r < 4; r++)
#pragma unroll
    for (int j = 0; j < NJ; j++) acc[r][j] = 0.f;

  for (int kb = 0; kb < 128; kb += 32) {
    __syncthreads();
#pragma unroll
    for (int q = 0; q < 2; q++) {
      int f = tid + q * 256;
      int row = f >> 3, kq = f & 7;
      float4 v = *(const float4*)(A + (size_t)(r0 + row) * 128 + kb + kq * 4);
      int bb = row * 33 + kq * 4;
      xs[bb + 0] = v.x; xs[bb + 1] = v.y; xs[bb + 2] = v.z; xs[bb + 3] = v.w;
    }
#pragma unroll
    for (int q = 0; q < WF4; q++) {
      int f = tid + q * 256;
      int k = f / (BC / 4), cq = f % (BC / 4);
      *(float4*)&wsh[k * BC + cq * 4] =
          *(const float4*)(W + (size_t)(kb + k) * BC + cq * 4);
    }
    __syncthreads();
#pragma unroll
    for (int kk = 0; kk < 32; kk++) {
      float av[4];
#pragma unroll
      for (int r = 0; r < 4; r++) av[r] = xs[(ty * 4 + r) * 33 + kk];
#pragma unroll
      for (int j = 0; j < NJ; j++) {
        float bv = wsh[kk * BC + tx + j * 16];
#pragma unroll
        for (int r = 0; r < 4; r++) acc[r][j] = fmaf(av[r], bv, acc[r][j]);
      }
    }
  }
#pragma unroll
  for (int r = 0; r < 4; r++) {
    int row = r0 + ty * 4 + r;
    float dr = dis[row];
#pragma unroll
    for (int j = 0; j < NJ; j++)
      out[(size_t)row * BC + tx + j * 16] = __float2bfloat16(acc[r][j] * dr);
  }
}

// ---------------------------------------------------------------- GEMM layer 2
__global__ __launch_bounds__(256) void gemm2_kernel(
    const unsigned short* __restrict__ A, const float* __restrict__ W,
    const float* __restrict__ sums, const float* __restrict__ g,
    const float* __restrict__ b, const float* __restrict__ dis,
    __hip_bfloat16* __restrict__ out) {
  constexpr int BC = 64, NJ = 4, WF4 = 2;
  __shared__ float xs[64 * 33];
  __shared__ float wsh[32 * BC];
  __shared__ float s_scl[128], s_shf[128];
  int tid = threadIdx.x;
  if (tid < 128) {
    float mean = sums[tid] / (float)kN;
    float var = sums[128 + tid] / (float)kN - mean * mean;
    float inv = rsqrtf(var + kEps);
    float sc = g[tid] * inv;
    s_scl[tid] = sc;
    s_shf[tid] = b[tid] - mean * sc;
  }
  int tx = tid & 15, ty = tid >> 4;
  int r0 = blockIdx.x * 64;
  float acc[4][NJ];
#pragma unroll
  for (int r = 0; r < 4; r++)
#pragma unroll
    for (int j = 0; j < NJ; j++) acc[r][j] = 0.f;

  for (int kb = 0; kb < 128; kb += 32) {
    __syncthreads();
    {
      int row = tid >> 2, kq = tid & 3;
      short8v v8 = *(const short8v*)(A + (size_t)(r0 + row) * 128 + kb + kq * 8);
      int bb = row * 33 + kq * 8;
#pragma unroll
      for (int j = 0; j < 8; j++) {
        int c = kb + kq * 8 + j;
        float v = bf2f((unsigned short)v8[j]);
        xs[bb + j] = fmaxf(0.f, fmaf(v, s_scl[c], s_shf[c]));
      }
    }
#pragma unroll
    for (int q = 0; q < WF4; q++) {
      int f = tid + q * 256;
      int k = f / (BC / 4), cq = f % (BC / 4);
      *(float4*)&wsh[k * BC + cq * 4] =
          *(const float4*)(W + (size_t)(kb + k) * BC + cq * 4);
    }
    __syncthreads();
#pragma unroll
    for (int kk = 0; kk < 32; kk++) {
      float av[4];
#pragma unroll
      for (int r = 0; r < 4; r++) av[r] = xs[(ty * 4 + r) * 33 + kk];
#pragma unroll
      for (int j = 0; j < NJ; j++) {
        float bv = wsh[kk * BC + tx + j * 16];
#pragma unroll
        for (int r = 0; r < 4; r++) acc[r][j] = fmaf(av[r], bv, acc[r][j]);
      }
    }
  }
#pragma unroll
  for (int r = 0; r < 4; r++) {
    int row = r0 + ty * 4 + r;
    float dr = dis[row];
#pragma unroll
    for (int j = 0; j < NJ; j++)
      out[(size_t)row * BC + tx + j * 16] = __float2bfloat16(acc[r][j] * dr);
  }
}

// ---------------------------------------------------------------- aggregation
__global__ __launch_bounds__(256) void agg1_kernel(const unsigned short* __restrict__ hs,
    const int* __restrict__ csr_src, const int* __restrict__ offsets,
    const int* __restrict__ counts, const float* __restrict__ dis,
    unsigned short* __restrict__ t1) {
  int tid = threadIdx.x;
  int wv = tid >> 6, lane = tid & 63;
  int d = blockIdx.x * 4 + wv;
  int g = lane >> 4, l = lane & 15;
  float acc[8];
  if (g == 0) {
    short8v v = *(const short8v*)(hs + (size_t)d * 128 + l * 8);
#pragma unroll
    for (int j = 0; j < 8; j++) acc[j] = bf2f((unsigned short)v[j]);
  } else {
#pragma unroll
    for (int j = 0; j < 8; j++) acc[j] = 0.f;
  }
  int s0 = offsets[d], n = counts[d];
  int i = g;
  for (; i + 4 < n; i += 8) {
    int sa = csr_src[s0 + i];
    int sb = csr_src[s0 + i + 4];
    short8v va = *(const short8v*)(hs + (size_t)sa * 128 + l * 8);
    short8v vb = *(const short8v*)(hs + (size_t)sb * 128 + l * 8);
#pragma unroll
    for (int j = 0; j < 8; j++) acc[j] += bf2f((unsigned short)va[j]);
#pragma unroll
    for (int j = 0; j < 8; j++) acc[j] += bf2f((unsigned short)vb[j]);
  }
  if (i < n) {
    int sa = csr_src[s0 + i];
    short8v va = *(const short8v*)(hs + (size_t)sa * 128 + l * 8);
#pragma unroll
    for (int j = 0; j < 8; j++) acc[j] += bf2f((unsigned short)va[j]);
  }
#pragma unroll
  for (int j = 0; j < 8; j++) {
    acc[j] += __shfl_xor(acc[j], 16, 64);
    acc[j] += __shfl_xor(acc[j], 32, 64);
  }
  if (g == 0) {
    float dd = dis[d];
    short8v o;
#pragma unroll
    for (int j = 0; j < 8; j++) o[j] = (short)f2bf(acc[j] * dd);
    *(short8v*)(t1 + (size_t)d * 128 + l * 8) = o;
  }
}

__global__ __launch_bounds__(256) void agg2_kernel(const unsigned short* __restrict__ hs,
    const int* __restrict__ csr_src, const int* __restrict__ offsets,
    const int* __restrict__ counts, const float* __restrict__ dis,
    float* __restrict__ t2) {
  int tid = threadIdx.x;
  int wv = tid >> 6, lane = tid & 63;
  int d = blockIdx.x * 4 + wv;
  int g = lane >> 3, l = lane & 7;
  float acc[8];
  if (g == 0) {
    short8v v = *(const short8v*)(hs + (size_t)d * 64 + l * 8);
#pragma unroll
    for (int j = 0; j < 8; j++) acc[j] = bf2f((unsigned short)v[j]);
  } else {
#pragma unroll
    for (int j = 0; j < 8; j++) acc[j] = 0.f;
  }
  int s0 = offsets[d], n = counts[d];
  int i = g;
  for (; i + 8 < n; i += 16) {
    int sa = csr_src[s0 + i];
    int sb = csr_src[s0 + i + 8];
    short8v va = *(const short8v*)(hs + (size_t)sa * 64 + l * 8);
    short8v vb = *(const short8v*)(hs + (size_t)sb * 64 + l * 8);
#pragma unroll
    for (int j = 0; j < 8; j++) acc[j] += bf2f((unsigned short)va[j]);
#pragma unroll
    for (int j = 0; j < 8; j++) acc[j] += bf2f((unsigned short)vb[j]);
  }
  if (i < n) {
    int sa = csr_src[s0 + i];
    short8v va = *(const short8v*)(hs + (size_t)sa * 64 + l * 8);
#pragma unroll
    for (int j = 0; j < 8; j++) acc[j] += bf2f((unsigned short)va[j]);
  }
#pragma unroll
  for (int j = 0; j < 8; j++) {
    acc[j] += __shfl_xor(acc[j], 8, 64);
    acc[j] += __shfl_xor(acc[j], 16, 64);
    acc[j] += __shfl_xor(acc[j], 32, 64);
  }
  if (g == 0) {
    float dd = dis[d];
    float* o = t2 + (size_t)d * 64 + l * 8;
    f32x4 o0 = {acc[0] * dd, acc[1] * dd, acc[2] * dd, acc[3] * dd};
    f32x4 o1 = {acc[4] * dd, acc[5] * dd, acc[6] * dd, acc[7] * dd};
    *(f32x4*)o = o0;
    *(f32x4*)(o + 4) = o1;
  }
}

// ---------------------------------------------------------------- BN stats
template <int C, bool BF16>
__global__ __launch_bounds__(256) void stats_kernel(const void* __restrict__ t,
                                                    float* __restrict__ sums) {
  constexpr int RP = 256 / C;
  int c = threadIdx.x % C;
  int rr = threadIdx.x / C;
  float s = 0.f, s2 = 0.f;
  for (int r = blockIdx.x * RP + rr; r < kN; r += gridDim.x * RP) {
    float v;
    if constexpr (BF16) v = bf2f(((const unsigned short*)t)[(size_t)r * C + c]);
    else v = ((const float*)t)[(size_t)r * C + c];
    s += v;
    s2 += v * v;
  }
  atomicAdd(&sums[c], s);
  atomicAdd(&sums[C + c], s2);
}

// ---------------------------------------------------------------- z + heads (fused)
__global__ __launch_bounds__(256) void zheads_kernel(const float* __restrict__ t2,
    const float* __restrict__ sums, const float* __restrict__ gg,
    const float* __restrict__ bb2,
    const float* __restrict__ wbin, const float* __restrict__ bbin,
    const float* __restrict__ wmc, const float* __restrict__ bmc,
    const float* __restrict__ wcont, const float* __restrict__ bcont,
    float* __restrict__ out0, unsigned short* __restrict__ zb) {
  __shared__ float wT[30 * 64];
  __shared__ float bias[32];
  __shared__ float s_scl[64], s_shf[64];
  int tid = threadIdx.x;
  for (int idx = tid; idx < 1920; idx += 256) {
    int j = idx >> 6, k = idx & 63;
    const float* src = (j < 10) ? wbin : (j < 20) ? wmc : wcont;
    wT[idx] = src[k * 10 + (j % 10)];
  }
  if (tid < 30)
    bias[tid] = (tid < 10) ? bbin[tid] : (tid < 20) ? bmc[tid - 10] : bcont[tid - 20];
  if (tid < 64) {
    float mean = sums[tid] / (float)kN;
    float var = sums[64 + tid] / (float)kN - mean * mean;
    float inv = rsqrtf(var + kEps);
    float sc = gg[tid] * inv;
    s_scl[tid] = sc;
    s_shf[tid] = bb2[tid] - mean * sc;
  }
  __syncthreads();
  int n = blockIdx.x * 256 + tid;
  float zr[64];
  const float4* t4 = (const float4*)(t2 + (size_t)n * 64);
#pragma unroll
  for (int q = 0; q < 16; q++) {
    float4 v = t4[q];
    zr[4 * q + 0] = fmaxf(0.f, fmaf(v.x, s_scl[4 * q + 0], s_shf[4 * q + 0]));
    zr[4 * q + 1] = fmaxf(0.f, fmaf(v.y, s_scl[4 * q + 1], s_shf[4 * q + 1]));
    zr[4 * q + 2] = fmaxf(0.f, fmaf(v.z, s_scl[4 * q + 2], s_shf[4 * q + 2]));
    zr[4 * q + 3] = fmaxf(0.f, fmaf(v.w, s_scl[4 * q + 3], s_shf[4 * q + 3]));
  }
  unsigned short* zrow = zb + (size_t)n * 64;
#pragma unroll
  for (int q = 0; q < 8; q++) {
    short8v o;
#pragma unroll
    for (int j = 0; j < 8; j++) o[j] = (short)f2bf(zr[q * 8 + j]);
    *(short8v*)(zrow + q * 8) = o;
  }
  float acc[30];
#pragma unroll
  for (int j = 0; j < 30; j++) {
    float s = bias[j];
#pragma unroll
    for (int kc = 0; kc < 16; kc++) {
      f32x4 wv = *(const f32x4*)&wT[j * 64 + kc * 4];
      s = fmaf(zr[4 * kc + 0], wv.x, s);
      s = fmaf(zr[4 * kc + 1], wv.y, s);
      s = fmaf(zr[4 * kc + 2], wv.z, s);
      s = fmaf(zr[4 * kc + 3], wv.w, s);
    }
    acc[j] = s;
  }
  float* o = out0 + (size_t)n * 30;
#pragma unroll
  for (int j = 0; j < 10; j++) o[j] = 1.f / (1.f + expf(-acc[j]));
  float m1 = fmaxf(fmaxf(acc[10], acc[11]), fmaxf(acc[12], acc[13]));
  float e1[4], s1 = 0.f;
#pragma unroll
  for (int j = 0; j < 4; j++) { e1[j] = expf(acc[10 + j] - m1); s1 += e1[j]; }
#pragma unroll
  for (int j = 0; j < 4; j++) o[10 + j] = e1[j] / s1;
  float m2 = acc[14];
#pragma unroll
  for (int j = 15; j < 20; j++) m2 = fmaxf(m2, acc[j]);
  float e2[6], s2 = 0.f;
#pragma unroll
  for (int j = 0; j < 6; j++) { e2[j] = expf(acc[14 + j] - m2); s2 += e2[j]; }
#pragma unroll
  for (int j = 0; j < 6; j++) o[14 + j] = e2[j] / s2;
#pragma unroll
  for (int j = 0; j < 10; j++) o[20 + j] = acc[20 + j];
}

// ---------------------------------------------------------------- adj + edge (fused, heterogeneous blocks)
// blocks [0,1024): edge-feature MFMA path.
// blocks [1024, 1024+16384): adj = z z^T, 128x128 tile; per-ks frag staging
// and 4x 32-row LDS chunks keep VGPR<=128 and LDS at 16.9 KB -> 4 blocks/CU.
__global__ __launch_bounds__(256, 4) void adjedge_kernel(const short* __restrict__ zb,
    const int* __restrict__ srcs, const int* __restrict__ dsts,
    const short* __restrict__ wfr, const float* __restrict__ be,
    float* __restrict__ adj, float* __restrict__ eout) {
  __shared__ float cs[32 * 132];
  int tid = threadIdx.x;
  int wid = tid >> 6, lane = tid & 63;
  int lr = lane & 15, lg = lane >> 4;

  if (blockIdx.x < 1024) {
    // ---------------- edge path ----------------
    float* es = &cs[wid * 256];
    int gw = blockIdx.x * 4 + wid;       // 4096 waves total
    short8v bfr[4];
#pragma unroll
    for (int f = 0; f < 4; f++)
      bfr[f] = *(const short8v*)(wfr + ((size_t)f * 64 + lane) * 8);
    float bias = be[lr];
    for (int t = 0; t < 8; t++) {
      int e0 = (gw * 8 + t) * 16;
      int se = srcs[e0 + lr], de = dsts[e0 + lr];
      short8v a0 = *(const short8v*)(zb + (size_t)se * 64 + lg * 8);
      short8v a1 = *(const short8v*)(zb + (size_t)se * 64 + 32 + lg * 8);
      short8v a2 = *(const short8v*)(zb + (size_t)de * 64 + lg * 8);
      short8v a3 = *(const short8v*)(zb + (size_t)de * 64 + 32 + lg * 8);
      f32x4 acc = {0.f, 0.f, 0.f, 0.f};
      acc = __builtin_amdgcn_mfma_f32_16x16x32_bf16(a0, bfr[0], acc, 0, 0, 0);
      acc = __builtin_amdgcn_mfma_f32_16x16x32_bf16(a1, bfr[1], acc, 0, 0, 0);
      acc = __builtin_amdgcn_mfma_f32_16x16x32_bf16(a2, bfr[2], acc, 0, 0, 0);
      acc = __builtin_amdgcn_mfma_f32_16x16x32_bf16(a3, bfr[3], acc, 0, 0, 0);
#pragma unroll
      for (int r = 0; r < 4; r++)
        es[(lg * 4 + r) * 16 + lr] = acc[r] + bias;
      f32x4 v = *(const f32x4*)&es[lane * 4];
      *(f32x4*)(eout + (size_t)e0 * 16 + lane * 4) = v;
    }
    return;
  }

  // ---------------- adj path ----------------
  int bid = blockIdx.x - 1024;
  int brow = bid & 127, bcol = bid >> 7;
  int li0 = (wid >> 1) * 64;
  int lj0 = (wid & 1) * 64;
  int i0 = brow * 128 + li0;
  int j0 = bcol * 128 + lj0;
  f32x4 acc[4][4];
#pragma unroll
  for (int mt = 0; mt < 4; mt++)
#pragma unroll
    for (int nt = 0; nt < 4; nt++) {
      f32x4 zz = {0.f, 0.f, 0.f, 0.f};
      acc[mt][nt] = zz;
    }
#pragma unroll
  for (int ks = 0; ks < 2; ks++) {
    short8v a[4], b[4];
#pragma unroll
    for (int mt = 0; mt < 4; mt++)
      a[mt] = *(const short8v*)(zb + (size_t)(i0 + mt * 16 + lr) * 64 + ks * 32 + lg * 8);
#pragma unroll
    for (int nt = 0; nt < 4; nt++)
      b[nt] = *(const short8v*)(zb + (size_t)(j0 + nt * 16 + lr) * 64 + ks * 32 + lg * 8);
#pragma unroll
    for (int mt = 0; mt < 4; mt++)
#pragma unroll
      for (int nt = 0; nt < 4; nt++)
        acc[mt][nt] = __builtin_amdgcn_mfma_f32_16x16x32_bf16(a[mt], b[nt],
                                                              acc[mt][nt], 0, 0, 0);
  }
  // 4 chunks of 32 rows: stage in LDS, write coalesced.
#pragma unroll
  for (int c = 0; c < 4; c++) {
    int mtbase = 2 * c - (wid >> 1) * 4;  // wave's mt covering rows [32c,32c+32)
    if (mtbase >= 0 && mtbase < 4) {
#pragma unroll
      for (int mm = 0; mm < 2; mm++) {
        int mt = mtbase + mm;
#pragma unroll
        for (int nt = 0; nt < 4; nt++)
#pragma unroll
          for (int r = 0; r < 4; r++)
            cs[(li0 + mt * 16 + lg * 4 + r - 32 * c) * 132 + lj0 + nt * 16 + lr] =
                acc[mt][nt][r];
      }
    }
    __syncthreads();
    // copy out 32 rows x 128 cols = 1024 float4; 4 per thread
#pragma unroll
    for (int q = 0; q < 4; q++) {
      int idx = q * 256 + tid;
      int row = idx >> 5, c4 = idx & 31;
      f32x4 v = *(const f32x4*)&cs[row * 132 + c4 * 4];
      *(f32x4*)(adj + (size_t)(brow * 128 + c * 32 + row) * kN + bcol * 128 + c4 * 4) = v;
    }
    __syncthreads();
  }
}

// ---------------------------------------------------------------- launch
extern "C" void kernel_launch(void* const* d_in, const int* in_sizes, int n_in,
                              void* d_out, int out_size, void* d_ws, size_t ws_size,
                              hipStream_t stream) {
  const float* x      = (const float*)d_in[0];
  const int*   ei     = (const int*)d_in[1];
  const float* w1     = (const float*)d_in[3];
  const float* bn1_g  = (const float*)d_in[5];
  const float* bn1_b  = (const float*)d_in[6];
  const float* w2     = (const float*)d_in[7];
  const float* bn2_g  = (const float*)d_in[9];
  const float* bn2_b  = (const float*)d_in[10];
  const float* w_bin  = (const float*)d_in[11];
  const float* b_bin  = (const float*)d_in[12];
  const float* w_mc   = (const float*)d_in[13];
  const float* b_mc   = (const float*)d_in[14];
  const float* w_cont = (const float*)d_in[15];
  const float* b_cont = (const float*)d_in[16];
  const float* w_edge = (const float*)d_in[17];
  const float* b_edge = (const float*)d_in[18];

  float* out0 = (float*)d_out;
  float* adj  = out0 + (size_t)kN * 30;
  float* eout = adj + (size_t)kN * kN;

  char* wp = (char*)d_ws;
  auto alloc = [&](size_t bytes) {
    char* p = wp;
    wp += (bytes + 255) & ~(size_t)255;
    return p;
  };
  int*   counts  = (int*)alloc((size_t)kN * 4);
  int*   offsets = (int*)alloc((size_t)kN * 4);
  int*   pos     = (int*)alloc((size_t)kN * 4);
  int*   csr_src = (int*)alloc((size_t)kE * 4);
  float* dis     = (float*)alloc((size_t)kN * 4);
  float* sums1   = (float*)alloc(256 * 4);
  float* sums2   = (float*)alloc(128 * 4);
  unsigned short* hs1 = (unsigned short*)alloc((size_t)kN * 128 * 2);
  unsigned short* t1  = (unsigned short*)alloc((size_t)kN * 128 * 2);
  unsigned short* hs2 = (unsigned short*)alloc((size_t)kN * 64 * 2);
  float* t2      = (float*)alloc((size_t)kN * 64 * 4);
  unsigned short* zb  = (unsigned short*)alloc((size_t)kN * 64 * 2);
  __hip_bfloat16* wfr = (__hip_bfloat16*)alloc(2048 * 2);

  const int* esrc = ei;
  const int* edst = ei + kE;

  zero_kernel<<<dim3(64), dim3(256), 0, stream>>>(counts, sums1, sums2, w_edge, wfr);
  hist_kernel<<<dim3(2048), dim3(256), 0, stream>>>(edst, counts);
  scan_kernel<<<dim3(1), dim3(1024), 0, stream>>>(counts, offsets, pos, dis);
  fill_kernel<<<dim3(2048), dim3(256), 0, stream>>>(esrc, edst, pos, csr_src);

  gemm1_kernel<<<dim3(kN / 64), dim3(256), 0, stream>>>(
      x, w1, dis, (__hip_bfloat16*)hs1);
  agg1_kernel<<<dim3(kN / 4), dim3(256), 0, stream>>>(
      hs1, csr_src, offsets, counts, dis, t1);
  stats_kernel<128, true><<<dim3(256), dim3(256), 0, stream>>>(t1, sums1);

  gemm2_kernel<<<dim3(kN / 64), dim3(256), 0, stream>>>(
      t1, w2, sums1, bn1_g, bn1_b, dis, (__hip_bfloat16*)hs2);
  agg2_kernel<<<dim3(kN / 4), dim3(256), 0, stream>>>(
      hs2, csr_src, offsets, counts, dis, t2);
  stats_kernel<64, false><<<dim3(256), dim3(256), 0, stream>>>(t2, sums2);

  zheads_kernel<<<dim3(kN / 256), dim3(256), 0, stream>>>(
      t2, sums2, bn2_g, bn2_b, w_bin, b_bin, w_mc, b_mc, w_cont, b_cont, out0, zb);

  adjedge_kernel<<<dim3(1024 + 16384), dim3(256), 0, stream>>>(
      (const short*)zb, esrc, edst, (const short*)wfr, b_edge, adj, eout);
}

// Round 11
// 436.938 us; speedup vs baseline: 1.2472x; 1.2472x over previous
//
#include <hip/hip_runtime.h>
#include <hip/hip_bf16.h>
#include <math.h>

// GAE on MI355X. N=16384 nodes, E=524288 edges.
// R11: revert to R9 structure; adj path becomes 512 persistent blocks (2/CU)
// looping 32 tiles each, with next-tile fragment loads issued before the
// store phase (register-level cross-tile prefetch; loads precede stores in
// program order so the MFMA wait is vmcnt(16), not a cold drain).

constexpr int kN = 16384;
constexpr int kE = 524288;
constexpr float kEps = 1e-5f;

typedef __attribute__((ext_vector_type(8))) short short8v;   // 8 x bf16
typedef __attribute__((ext_vector_type(4))) float f32x4;

__device__ inline float bf2f(unsigned short u) {
  return __uint_as_float(((unsigned)u) << 16);
}
__device__ inline unsigned short f2bf(float f) {  // RNE
  unsigned u = __float_as_uint(f);
  return (unsigned short)((u + 0x7fff + ((u >> 16) & 1)) >> 16);
}

// ---------------------------------------------------------------- utility
__global__ void zero_kernel(int* counts, float* sums1, float* sums2,
                            const float* __restrict__ we, __hip_bfloat16* wfr) {
  int i = blockIdx.x * 256 + threadIdx.x;
  if (i < kN) counts[i] = 0;
  if (i < 256) sums1[i] = 0.f;
  if (i < 128) sums2[i] = 0.f;
  if (i < 2048) {
    int f = i >> 9, l = (i >> 3) & 63, j = i & 7;
    int lr = l & 15, lg = l >> 4;
    int krow = f * 32 + lg * 8 + j;
    wfr[i] = __float2bfloat16(we[krow * 16 + lr]);
  }
}

__global__ void hist_kernel(const int* __restrict__ dst, int* __restrict__ counts) {
  int e = blockIdx.x * 256 + threadIdx.x;
  if (e < kE) atomicAdd(&counts[dst[e]], 1);
}

__global__ __launch_bounds__(1024) void scan_kernel(const int* __restrict__ counts,
    int* __restrict__ offsets, int* __restrict__ pos, float* __restrict__ dis) {
  __shared__ int wave_tot[16];
  int tid = threadIdx.x;
  int base = tid * 16;
  int loc[16];
  int s = 0;
#pragma unroll
  for (int i = 0; i < 16; i++) { loc[i] = s; s += counts[base + i]; }
  int lane = tid & 63, wv = tid >> 6;
  int incl = s;
#pragma unroll
  for (int d = 1; d < 64; d <<= 1) {
    int v = __shfl_up(incl, d, 64);
    if (lane >= d) incl += v;
  }
  if (lane == 63) wave_tot[wv] = incl;
  __syncthreads();
  int woff = 0;
  for (int i = 0; i < wv; i++) woff += wave_tot[i];
  int excl = woff + incl - s;
#pragma unroll
  for (int i = 0; i < 16; i++) {
    int o = excl + loc[i];
    offsets[base + i] = o;
    pos[base + i] = o;
    dis[base + i] = rsqrtf((float)counts[base + i] + 1.0f);  // +1 self-loop
  }
}

__global__ void fill_kernel(const int* __restrict__ src, const int* __restrict__ dst,
                            int* __restrict__ pos, int* __restrict__ csr_src) {
  int e = blockIdx.x * 256 + threadIdx.x;
  if (e < kE) {
    int d = dst[e];
    int p = atomicAdd(&pos[d], 1);
    csr_src[p] = src[e];
  }
}

// ---------------------------------------------------------------- GEMM layer 1
__global__ __launch_bounds__(256) void gemm1_kernel(
    const float* __restrict__ A, const float* __restrict__ W,
    const float* __restrict__ dis, __hip_bfloat16* __restrict__ out) {
  constexpr int BC = 128, NJ = 8, WF4 = 4;
  __shared__ float xs[64 * 33];
  __shared__ float wsh[32 * BC];
  int tid = threadIdx.x;
  int tx = tid & 15, ty = tid >> 4;
  int r0 = blockIdx.x * 64;
  float acc[4][NJ];
#pragma unroll
  for (int r = 0; r < 4; r++)
#pragma unroll
    for (int j = 0; j < NJ; j++) acc[r][j] = 0.f;

  for (int kb = 0; kb < 128; kb += 32) {
    __syncthreads();
#pragma unroll
    for (int q = 0; q < 2; q++) {
      int f = tid + q * 256;
      int row = f >> 3, kq = f & 7;
      float4 v = *(const float4*)(A + (size_t)(r0 + row) * 128 + kb + kq * 4);
      int bb = row * 33 + kq * 4;
      xs[bb + 0] = v.x; xs[bb + 1] = v.y; xs[bb + 2] = v.z; xs[bb + 3] = v.w;
    }
#pragma unroll
    for (int q = 0; q < WF4; q++) {
      int f = tid + q * 256;
      int k = f / (BC / 4), cq = f % (BC / 4);
      *(float4*)&wsh[k * BC + cq * 4] =
          *(const float4*)(W + (size_t)(kb + k) * BC + cq * 4);
    }
    __syncthreads();
#pragma unroll
    for (int kk = 0; kk < 32; kk++) {
      float av[4];
#pragma unroll
      for (int r = 0; r < 4; r++) av[r] = xs[(ty * 4 + r) * 33 + kk];
#pragma unroll
      for (int j = 0; j < NJ; j++) {
        float bv = wsh[kk * BC + tx + j * 16];
#pragma unroll
        for (int r = 0; r < 4; r++) acc[r][j] = fmaf(av[r], bv, acc[r][j]);
      }
    }
  }
#pragma unroll
  for (int r = 0; r < 4; r++) {
    int row = r0 + ty * 4 + r;
    float dr = dis[row];
#pragma unroll
    for (int j = 0; j < NJ; j++)
      out[(size_t)row * BC + tx + j * 16] = __float2bfloat16(acc[r][j] * dr);
  }
}

// ---------------------------------------------------------------- GEMM layer 2
__global__ __launch_bounds__(256) void gemm2_kernel(
    const unsigned short* __restrict__ A, const float* __restrict__ W,
    const float* __restrict__ sums, const float* __restrict__ g,
    const float* __restrict__ b, const float* __restrict__ dis,
    __hip_bfloat16* __restrict__ out) {
  constexpr int BC = 64, NJ = 4, WF4 = 2;
  __shared__ float xs[64 * 33];
  __shared__ float wsh[32 * BC];
  __shared__ float s_scl[128], s_shf[128];
  int tid = threadIdx.x;
  if (tid < 128) {
    float mean = sums[tid] / (float)kN;
    float var = sums[128 + tid] / (float)kN - mean * mean;
    float inv = rsqrtf(var + kEps);
    float sc = g[tid] * inv;
    s_scl[tid] = sc;
    s_shf[tid] = b[tid] - mean * sc;
  }
  int tx = tid & 15, ty = tid >> 4;
  int r0 = blockIdx.x * 64;
  float acc[4][NJ];
#pragma unroll
  for (int r = 0; r < 4; r++)
#pragma unroll
    for (int j = 0; j < NJ; j++) acc[r][j] = 0.f;

  for (int kb = 0; kb < 128; kb += 32) {
    __syncthreads();
    {
      int row = tid >> 2, kq = tid & 3;
      short8v v8 = *(const short8v*)(A + (size_t)(r0 + row) * 128 + kb + kq * 8);
      int bb = row * 33 + kq * 8;
#pragma unroll
      for (int j = 0; j < 8; j++) {
        int c = kb + kq * 8 + j;
        float v = bf2f((unsigned short)v8[j]);
        xs[bb + j] = fmaxf(0.f, fmaf(v, s_scl[c], s_shf[c]));
      }
    }
#pragma unroll
    for (int q = 0; q < WF4; q++) {
      int f = tid + q * 256;
      int k = f / (BC / 4), cq = f % (BC / 4);
      *(float4*)&wsh[k * BC + cq * 4] =
          *(const float4*)(W + (size_t)(kb + k) * BC + cq * 4);
    }
    __syncthreads();
#pragma unroll
    for (int kk = 0; kk < 32; kk++) {
      float av[4];
#pragma unroll
      for (int r = 0; r < 4; r++) av[r] = xs[(ty * 4 + r) * 33 + kk];
#pragma unroll
      for (int j = 0; j < NJ; j++) {
        float bv = wsh[kk * BC + tx + j * 16];
#pragma unroll
        for (int r = 0; r < 4; r++) acc[r][j] = fmaf(av[r], bv, acc[r][j]);
      }
    }
  }
#pragma unroll
  for (int r = 0; r < 4; r++) {
    int row = r0 + ty * 4 + r;
    float dr = dis[row];
#pragma unroll
    for (int j = 0; j < NJ; j++)
      out[(size_t)row * BC + tx + j * 16] = __float2bfloat16(acc[r][j] * dr);
  }
}

// ---------------------------------------------------------------- aggregation
__global__ __launch_bounds__(256) void agg1_kernel(const unsigned short* __restrict__ hs,
    const int* __restrict__ csr_src, const int* __restrict__ offsets,
    const int* __restrict__ counts, const float* __restrict__ dis,
    unsigned short* __restrict__ t1) {
  int tid = threadIdx.x;
  int wv = tid >> 6, lane = tid & 63;
  int d = blockIdx.x * 4 + wv;
  int g = lane >> 4, l = lane & 15;
  float acc[8];
  if (g == 0) {
    short8v v = *(const short8v*)(hs + (size_t)d * 128 + l * 8);
#pragma unroll
    for (int j = 0; j < 8; j++) acc[j] = bf2f((unsigned short)v[j]);
  } else {
#pragma unroll
    for (int j = 0; j < 8; j++) acc[j] = 0.f;
  }
  int s0 = offsets[d], n = counts[d];
  int i = g;
  for (; i + 4 < n; i += 8) {
    int sa = csr_src[s0 + i];
    int sb = csr_src[s0 + i + 4];
    short8v va = *(const short8v*)(hs + (size_t)sa * 128 + l * 8);
    short8v vb = *(const short8v*)(hs + (size_t)sb * 128 + l * 8);
#pragma unroll
    for (int j = 0; j < 8; j++) acc[j] += bf2f((unsigned short)va[j]);
#pragma unroll
    for (int j = 0; j < 8; j++) acc[j] += bf2f((unsigned short)vb[j]);
  }
  if (i < n) {
    int sa = csr_src[s0 + i];
    short8v va = *(const short8v*)(hs + (size_t)sa * 128 + l * 8);
#pragma unroll
    for (int j = 0; j < 8; j++) acc[j] += bf2f((unsigned short)va[j]);
  }
#pragma unroll
  for (int j = 0; j < 8; j++) {
    acc[j] += __shfl_xor(acc[j], 16, 64);
    acc[j] += __shfl_xor(acc[j], 32, 64);
  }
  if (g == 0) {
    float dd = dis[d];
    short8v o;
#pragma unroll
    for (int j = 0; j < 8; j++) o[j] = (short)f2bf(acc[j] * dd);
    *(short8v*)(t1 + (size_t)d * 128 + l * 8) = o;
  }
}

__global__ __launch_bounds__(256) void agg2_kernel(const unsigned short* __restrict__ hs,
    const int* __restrict__ csr_src, const int* __restrict__ offsets,
    const int* __restrict__ counts, const float* __restrict__ dis,
    float* __restrict__ t2) {
  int tid = threadIdx.x;
  int wv = tid >> 6, lane = tid & 63;
  int d = blockIdx.x * 4 + wv;
  int g = lane >> 3, l = lane & 7;
  float acc[8];
  if (g == 0) {
    short8v v = *(const short8v*)(hs + (size_t)d * 64 + l * 8);
#pragma unroll
    for (int j = 0; j < 8; j++) acc[j] = bf2f((unsigned short)v[j]);
  } else {
#pragma unroll
    for (int j = 0; j < 8; j++) acc[j] = 0.f;
  }
  int s0 = offsets[d], n = counts[d];
  int i = g;
  for (; i + 8 < n; i += 16) {
    int sa = csr_src[s0 + i];
    int sb = csr_src[s0 + i + 8];
    short8v va = *(const short8v*)(hs + (size_t)sa * 64 + l * 8);
    short8v vb = *(const short8v*)(hs + (size_t)sb * 64 + l * 8);
#pragma unroll
    for (int j = 0; j < 8; j++) acc[j] += bf2f((unsigned short)va[j]);
#pragma unroll
    for (int j = 0; j < 8; j++) acc[j] += bf2f((unsigned short)vb[j]);
  }
  if (i < n) {
    int sa = csr_src[s0 + i];
    short8v va = *(const short8v*)(hs + (size_t)sa * 64 + l * 8);
#pragma unroll
    for (int j = 0; j < 8; j++) acc[j] += bf2f((unsigned short)va[j]);
  }
#pragma unroll
  for (int j = 0; j < 8; j++) {
    acc[j] += __shfl_xor(acc[j], 8, 64);
    acc[j] += __shfl_xor(acc[j], 16, 64);
    acc[j] += __shfl_xor(acc[j], 32, 64);
  }
  if (g == 0) {
    float dd = dis[d];
    float* o = t2 + (size_t)d * 64 + l * 8;
    f32x4 o0 = {acc[0] * dd, acc[1] * dd, acc[2] * dd, acc[3] * dd};
    f32x4 o1 = {acc[4] * dd, acc[5] * dd, acc[6] * dd, acc[7] * dd};
    *(f32x4*)o = o0;
    *(f32x4*)(o + 4) = o1;
  }
}

// ---------------------------------------------------------------- BN stats
template <int C, bool BF16>
__global__ __launch_bounds__(256) void stats_kernel(const void* __restrict__ t,
                                                    float* __restrict__ sums) {
  constexpr int RP = 256 / C;
  int c = threadIdx.x % C;
  int rr = threadIdx.x / C;
  float s = 0.f, s2 = 0.f;
  for (int r = blockIdx.x * RP + rr; r < kN; r += gridDim.x * RP) {
    float v;
    if constexpr (BF16) v = bf2f(((const unsigned short*)t)[(size_t)r * C + c]);
    else v = ((const float*)t)[(size_t)r * C + c];
    s += v;
    s2 += v * v;
  }
  atomicAdd(&sums[c], s);
  atomicAdd(&sums[C + c], s2);
}

// ---------------------------------------------------------------- z + heads (fused)
__global__ __launch_bounds__(256) void zheads_kernel(const float* __restrict__ t2,
    const float* __restrict__ sums, const float* __restrict__ gg,
    const float* __restrict__ bb2,
    const float* __restrict__ wbin, const float* __restrict__ bbin,
    const float* __restrict__ wmc, const float* __restrict__ bmc,
    const float* __restrict__ wcont, const float* __restrict__ bcont,
    float* __restrict__ out0, unsigned short* __restrict__ zb) {
  __shared__ float wT[30 * 64];
  __shared__ float bias[32];
  __shared__ float s_scl[64], s_shf[64];
  int tid = threadIdx.x;
  for (int idx = tid; idx < 1920; idx += 256) {
    int j = idx >> 6, k = idx & 63;
    const float* src = (j < 10) ? wbin : (j < 20) ? wmc : wcont;
    wT[idx] = src[k * 10 + (j % 10)];
  }
  if (tid < 30)
    bias[tid] = (tid < 10) ? bbin[tid] : (tid < 20) ? bmc[tid - 10] : bcont[tid - 20];
  if (tid < 64) {
    float mean = sums[tid] / (float)kN;
    float var = sums[64 + tid] / (float)kN - mean * mean;
    float inv = rsqrtf(var + kEps);
    float sc = gg[tid] * inv;
    s_scl[tid] = sc;
    s_shf[tid] = bb2[tid] - mean * sc;
  }
  __syncthreads();
  int n = blockIdx.x * 256 + tid;
  float zr[64];
  const float4* t4 = (const float4*)(t2 + (size_t)n * 64);
#pragma unroll
  for (int q = 0; q < 16; q++) {
    float4 v = t4[q];
    zr[4 * q + 0] = fmaxf(0.f, fmaf(v.x, s_scl[4 * q + 0], s_shf[4 * q + 0]));
    zr[4 * q + 1] = fmaxf(0.f, fmaf(v.y, s_scl[4 * q + 1], s_shf[4 * q + 1]));
    zr[4 * q + 2] = fmaxf(0.f, fmaf(v.z, s_scl[4 * q + 2], s_shf[4 * q + 2]));
    zr[4 * q + 3] = fmaxf(0.f, fmaf(v.w, s_scl[4 * q + 3], s_shf[4 * q + 3]));
  }
  unsigned short* zrow = zb + (size_t)n * 64;
#pragma unroll
  for (int q = 0; q < 8; q++) {
    short8v o;
#pragma unroll
    for (int j = 0; j < 8; j++) o[j] = (short)f2bf(zr[q * 8 + j]);
    *(short8v*)(zrow + q * 8) = o;
  }
  float acc[30];
#pragma unroll
  for (int j = 0; j < 30; j++) {
    float s = bias[j];
#pragma unroll
    for (int kc = 0; kc < 16; kc++) {
      f32x4 wv = *(const f32x4*)&wT[j * 64 + kc * 4];
      s = fmaf(zr[4 * kc + 0], wv.x, s);
      s = fmaf(zr[4 * kc + 1], wv.y, s);
      s = fmaf(zr[4 * kc + 2], wv.z, s);
      s = fmaf(zr[4 * kc + 3], wv.w, s);
    }
    acc[j] = s;
  }
  float* o = out0 + (size_t)n * 30;
#pragma unroll
  for (int j = 0; j < 10; j++) o[j] = 1.f / (1.f + expf(-acc[j]));
  float m1 = fmaxf(fmaxf(acc[10], acc[11]), fmaxf(acc[12], acc[13]));
  float e1[4], s1 = 0.f;
#pragma unroll
  for (int j = 0; j < 4; j++) { e1[j] = expf(acc[10 + j] - m1); s1 += e1[j]; }
#pragma unroll
  for (int j = 0; j < 4; j++) o[10 + j] = e1[j] / s1;
  float m2 = acc[14];
#pragma unroll
  for (int j = 15; j < 20; j++) m2 = fmaxf(m2, acc[j]);
  float e2[6], s2 = 0.f;
#pragma unroll
  for (int j = 0; j < 6; j++) { e2[j] = expf(acc[14 + j] - m2); s2 += e2[j]; }
#pragma unroll
  for (int j = 0; j < 6; j++) o[14 + j] = e2[j] / s2;
#pragma unroll
  for (int j = 0; j < 10; j++) o[20 + j] = acc[20 + j];
}

// ---------------------------------------------------------------- adj + edge (fused)
// blocks [0,1024): edge-feature MFMA path.
// blocks [1024,1536): persistent adj blocks; each loops 32 tiles (stride 512).
// Next-tile fragment loads issued after barriers and BEFORE the store phase:
// the 16-store phase hides the L2 fetch latency; next MFMA waits vmcnt(16).
__global__ __launch_bounds__(256) void adjedge_kernel(const short* __restrict__ zb,
    const int* __restrict__ srcs, const int* __restrict__ dsts,
    const short* __restrict__ wfr, const float* __restrict__ be,
    float* __restrict__ adj, float* __restrict__ eout) {
  __shared__ float cs[128 * 132];
  int tid = threadIdx.x;
  int wid = tid >> 6, lane = tid & 63;
  int lr = lane & 15, lg = lane >> 4;

  if (blockIdx.x < 1024) {
    // ---------------- edge path ----------------
    float* es = &cs[wid * 256];
    int gw = blockIdx.x * 4 + wid;       // 4096 waves total
    short8v bfr[4];
#pragma unroll
    for (int f = 0; f < 4; f++)
      bfr[f] = *(const short8v*)(wfr + ((size_t)f * 64 + lane) * 8);
    float bias = be[lr];
    for (int t = 0; t < 8; t++) {
      int e0 = (gw * 8 + t) * 16;
      int se = srcs[e0 + lr], de = dsts[e0 + lr];
      short8v a0 = *(const short8v*)(zb + (size_t)se * 64 + lg * 8);
      short8v a1 = *(const short8v*)(zb + (size_t)se * 64 + 32 + lg * 8);
      short8v a2 = *(const short8v*)(zb + (size_t)de * 64 + lg * 8);
      short8v a3 = *(const short8v*)(zb + (size_t)de * 64 + 32 + lg * 8);
      f32x4 acc = {0.f, 0.f, 0.f, 0.f};
      acc = __builtin_amdgcn_mfma_f32_16x16x32_bf16(a0, bfr[0], acc, 0, 0, 0);
      acc = __builtin_amdgcn_mfma_f32_16x16x32_bf16(a1, bfr[1], acc, 0, 0, 0);
      acc = __builtin_amdgcn_mfma_f32_16x16x32_bf16(a2, bfr[2], acc, 0, 0, 0);
      acc = __builtin_amdgcn_mfma_f32_16x16x32_bf16(a3, bfr[3], acc, 0, 0, 0);
#pragma unroll
      for (int r = 0; r < 4; r++)
        es[(lg * 4 + r) * 16 + lr] = acc[r] + bias;
      f32x4 v = *(const f32x4*)&es[lane * 4];
      *(f32x4*)(eout + (size_t)e0 * 16 + lane * 4) = v;
    }
    return;
  }

  // ---------------- adj path (persistent, register-pipelined) ----------------
  int p = blockIdx.x - 1024;            // 0..511
  int li0 = (wid >> 1) * 64;
  int lj0 = (wid & 1) * 64;
  short8v a[4][2], b[4][2];
  {
    int i0 = (p & 127) * 128 + li0;
    int j0 = (p >> 7) * 128 + lj0;
#pragma unroll
    for (int mt = 0; mt < 4; mt++)
#pragma unroll
      for (int ks = 0; ks < 2; ks++)
        a[mt][ks] = *(const short8v*)(zb + (size_t)(i0 + mt * 16 + lr) * 64 + ks * 32 + lg * 8);
#pragma unroll
    for (int nt = 0; nt < 4; nt++)
#pragma unroll
      for (int ks = 0; ks < 2; ks++)
        b[nt][ks] = *(const short8v*)(zb + (size_t)(j0 + nt * 16 + lr) * 64 + ks * 32 + lg * 8);
  }
  for (int t = p; t < 16384; t += 512) {
    f32x4 acc[4][4];
#pragma unroll
    for (int mt = 0; mt < 4; mt++)
#pragma unroll
      for (int nt = 0; nt < 4; nt++) {
        f32x4 zz = {0.f, 0.f, 0.f, 0.f};
        acc[mt][nt] = zz;
      }
#pragma unroll
    for (int ks = 0; ks < 2; ks++)
#pragma unroll
      for (int mt = 0; mt < 4; mt++)
#pragma unroll
        for (int nt = 0; nt < 4; nt++)
          acc[mt][nt] = __builtin_amdgcn_mfma_f32_16x16x32_bf16(a[mt][ks], b[nt][ks],
                                                                acc[mt][nt], 0, 0, 0);
    __syncthreads();  // previous iteration's LDS readers done
#pragma unroll
    for (int mt = 0; mt < 4; mt++)
#pragma unroll
      for (int nt = 0; nt < 4; nt++)
#pragma unroll
        for (int r = 0; r < 4; r++)
          cs[(li0 + mt * 16 + lg * 4 + r) * 132 + lj0 + nt * 16 + lr] = acc[mt][nt][r];
    __syncthreads();  // LDS visible
    // prefetch next tile's fragments (issued before the store phase)
    int tn = t + 512;
    if (tn < 16384) {
      int i0 = (tn & 127) * 128 + li0;
      int j0 = (tn >> 7) * 128 + lj0;
#pragma unroll
      for (int mt = 0; mt < 4; mt++)
#pragma unroll
        for (int ks = 0; ks < 2; ks++)
          a[mt][ks] = *(const short8v*)(zb + (size_t)(i0 + mt * 16 + lr) * 64 + ks * 32 + lg * 8);
#pragma unroll
      for (int nt = 0; nt < 4; nt++)
#pragma unroll
        for (int ks = 0; ks < 2; ks++)
          b[nt][ks] = *(const short8v*)(zb + (size_t)(j0 + nt * 16 + lr) * 64 + ks * 32 + lg * 8);
    }
    // store phase: 128x128 tile, 1 KB/wave coalesced float4 stores
    int row = tid >> 5;
    int c4 = tid & 31;
    size_t gbase = (size_t)((t & 127) * 128 + row) * kN + (t >> 7) * 128 + c4 * 4;
    const float* lbase = &cs[row * 132 + c4 * 4];
#pragma unroll
    for (int it = 0; it < 16; it++) {
      f32x4 v = *(const f32x4*)(lbase + it * 8 * 132);
      *(f32x4*)(adj + gbase + (size_t)it * 8 * kN) = v;
    }
  }
}

// ---------------------------------------------------------------- launch
extern "C" void kernel_launch(void* const* d_in, const int* in_sizes, int n_in,
                              void* d_out, int out_size, void* d_ws, size_t ws_size,
                              hipStream_t stream) {
  const float* x      = (const float*)d_in[0];
  const int*   ei     = (const int*)d_in[1];
  const float* w1     = (const float*)d_in[3];
  const float* bn1_g  = (const float*)d_in[5];
  const float* bn1_b  = (const float*)d_in[6];
  const float* w2     = (const float*)d_in[7];
  const float* bn2_g  = (const float*)d_in[9];
  const float* bn2_b  = (const float*)d_in[10];
  const float* w_bin  = (const float*)d_in[11];
  const float* b_bin  = (const float*)d_in[12];
  const float* w_mc   = (const float*)d_in[13];
  const float* b_mc   = (const float*)d_in[14];
  const float* w_cont = (const float*)d_in[15];
  const float* b_cont = (const float*)d_in[16];
  const float* w_edge = (const float*)d_in[17];
  const float* b_edge = (const float*)d_in[18];

  float* out0 = (float*)d_out;
  float* adj  = out0 + (size_t)kN * 30;
  float* eout = adj + (size_t)kN * kN;

  char* wp = (char*)d_ws;
  auto alloc = [&](size_t bytes) {
    char* p = wp;
    wp += (bytes + 255) & ~(size_t)255;
    return p;
  };
  int*   counts  = (int*)alloc((size_t)kN * 4);
  int*   offsets = (int*)alloc((size_t)kN * 4);
  int*   pos     = (int*)alloc((size_t)kN * 4);
  int*   csr_src = (int*)alloc((size_t)kE * 4);
  float* dis     = (float*)alloc((size_t)kN * 4);
  float* sums1   = (float*)alloc(256 * 4);
  float* sums2   = (float*)alloc(128 * 4);
  unsigned short* hs1 = (unsigned short*)alloc((size_t)kN * 128 * 2);
  unsigned short* t1  = (unsigned short*)alloc((size_t)kN * 128 * 2);
  unsigned short* hs2 = (unsigned short*)alloc((size_t)kN * 64 * 2);
  float* t2      = (float*)alloc((size_t)kN * 64 * 4);
  unsigned short* zb  = (unsigned short*)alloc((size_t)kN * 64 * 2);
  __hip_bfloat16* wfr = (__hip_bfloat16*)alloc(2048 * 2);

  const int* esrc = ei;
  const int* edst = ei + kE;

  zero_kernel<<<dim3(64), dim3(256), 0, stream>>>(counts, sums1, sums2, w_edge, wfr);
  hist_kernel<<<dim3(2048), dim3(256), 0, stream>>>(edst, counts);
  scan_kernel<<<dim3(1), dim3(1024), 0, stream>>>(counts, offsets, pos, dis);
  fill_kernel<<<dim3(2048), dim3(256), 0, stream>>>(esrc, edst, pos, csr_src);

  gemm1_kernel<<<dim3(kN / 64), dim3(256), 0, stream>>>(
      x, w1, dis, (__hip_bfloat16*)hs1);
  agg1_kernel<<<dim3(kN / 4), dim3(256), 0, stream>>>(
      hs1, csr_src, offsets, counts, dis, t1);
  stats_kernel<128, true><<<dim3(256), dim3(256), 0, stream>>>(t1, sums1);

  gemm2_kernel<<<dim3(kN / 64), dim3(256), 0, stream>>>(
      t1, w2, sums1, bn1_g, bn1_b, dis, (__hip_bfloat16*)hs2);
  agg2_kernel<<<dim3(kN / 4), dim3(256), 0, stream>>>(
      hs2, csr_src, offsets, counts, dis, t2);
  stats_kernel<64, false><<<dim3(256), dim3(256), 0, stream>>>(t2, sums2);

  zheads_kernel<<<dim3(kN / 256), dim3(256), 0, stream>>>(
      t2, sums2, bn2_g, bn2_b, w_bin, b_bin, w_mc, b_mc, w_cont, b_cont, out0, zb);

  adjedge_kernel<<<dim3(1024 + 512), dim3(256), 0, stream>>>(
      (const short*)zb, esrc, edst, (const short*)wfr, b_edge, adj, eout);
}

// Round 12
// 422.298 us; speedup vs baseline: 1.2904x; 1.0347x over previous
//
#include <hip/hip_runtime.h>
#include <hip/hip_bf16.h>
#include <math.h>

// GAE on MI355X. N=16384 nodes, E=524288 edges.
// R12: exact R9 structure; single change: adj block mapping brow-fast ->
// bcol-fast so the ~512 concurrently-resident adj blocks write one
// contiguous 512-row (32 MB) band instead of 2 KB fragments scattered
// across all 16384 output rows (isolates R8's band effect from its
// tile-shape regression).

constexpr int kN = 16384;
constexpr int kE = 524288;
constexpr float kEps = 1e-5f;

typedef __attribute__((ext_vector_type(8))) short short8v;   // 8 x bf16
typedef __attribute__((ext_vector_type(4))) float f32x4;

__device__ inline float bf2f(unsigned short u) {
  return __uint_as_float(((unsigned)u) << 16);
}
__device__ inline unsigned short f2bf(float f) {  // RNE
  unsigned u = __float_as_uint(f);
  return (unsigned short)((u + 0x7fff + ((u >> 16) & 1)) >> 16);
}

// ---------------------------------------------------------------- utility
__global__ void zero_kernel(int* counts, float* sums1, float* sums2,
                            const float* __restrict__ we, __hip_bfloat16* wfr) {
  int i = blockIdx.x * 256 + threadIdx.x;
  if (i < kN) counts[i] = 0;
  if (i < 256) sums1[i] = 0.f;
  if (i < 128) sums2[i] = 0.f;
  if (i < 2048) {
    int f = i >> 9, l = (i >> 3) & 63, j = i & 7;
    int lr = l & 15, lg = l >> 4;
    int krow = f * 32 + lg * 8 + j;
    wfr[i] = __float2bfloat16(we[krow * 16 + lr]);
  }
}

__global__ void hist_kernel(const int* __restrict__ dst, int* __restrict__ counts) {
  int e = blockIdx.x * 256 + threadIdx.x;
  if (e < kE) atomicAdd(&counts[dst[e]], 1);
}

__global__ __launch_bounds__(1024) void scan_kernel(const int* __restrict__ counts,
    int* __restrict__ offsets, int* __restrict__ pos, float* __restrict__ dis) {
  __shared__ int wave_tot[16];
  int tid = threadIdx.x;
  int base = tid * 16;
  int loc[16];
  int s = 0;
#pragma unroll
  for (int i = 0; i < 16; i++) { loc[i] = s; s += counts[base + i]; }
  int lane = tid & 63, wv = tid >> 6;
  int incl = s;
#pragma unroll
  for (int d = 1; d < 64; d <<= 1) {
    int v = __shfl_up(incl, d, 64);
    if (lane >= d) incl += v;
  }
  if (lane == 63) wave_tot[wv] = incl;
  __syncthreads();
  int woff = 0;
  for (int i = 0; i < wv; i++) woff += wave_tot[i];
  int excl = woff + incl - s;
#pragma unroll
  for (int i = 0; i < 16; i++) {
    int o = excl + loc[i];
    offsets[base + i] = o;
    pos[base + i] = o;
    dis[base + i] = rsqrtf((float)counts[base + i] + 1.0f);  // +1 self-loop
  }
}

__global__ void fill_kernel(const int* __restrict__ src, const int* __restrict__ dst,
                            int* __restrict__ pos, int* __restrict__ csr_src) {
  int e = blockIdx.x * 256 + threadIdx.x;
  if (e < kE) {
    int d = dst[e];
    int p = atomicAdd(&pos[d], 1);
    csr_src[p] = src[e];
  }
}

// ---------------------------------------------------------------- GEMM layer 1
__global__ __launch_bounds__(256) void gemm1_kernel(
    const float* __restrict__ A, const float* __restrict__ W,
    const float* __restrict__ dis, __hip_bfloat16* __restrict__ out) {
  constexpr int BC = 128, NJ = 8, WF4 = 4;
  __shared__ float xs[64 * 33];
  __shared__ float wsh[32 * BC];
  int tid = threadIdx.x;
  int tx = tid & 15, ty = tid >> 4;
  int r0 = blockIdx.x * 64;
  float acc[4][NJ];
#pragma unroll
  for (int r = 0; r < 4; r++)
#pragma unroll
    for (int j = 0; j < NJ; j++) acc[r][j] = 0.f;

  for (int kb = 0; kb < 128; kb += 32) {
    __syncthreads();
#pragma unroll
    for (int q = 0; q < 2; q++) {
      int f = tid + q * 256;
      int row = f >> 3, kq = f & 7;
      float4 v = *(const float4*)(A + (size_t)(r0 + row) * 128 + kb + kq * 4);
      int bb = row * 33 + kq * 4;
      xs[bb + 0] = v.x; xs[bb + 1] = v.y; xs[bb + 2] = v.z; xs[bb + 3] = v.w;
    }
#pragma unroll
    for (int q = 0; q < WF4; q++) {
      int f = tid + q * 256;
      int k = f / (BC / 4), cq = f % (BC / 4);
      *(float4*)&wsh[k * BC + cq * 4] =
          *(const float4*)(W + (size_t)(kb + k) * BC + cq * 4);
    }
    __syncthreads();
#pragma unroll
    for (int kk = 0; kk < 32; kk++) {
      float av[4];
#pragma unroll
      for (int r = 0; r < 4; r++) av[r] = xs[(ty * 4 + r) * 33 + kk];
#pragma unroll
      for (int j = 0; j < NJ; j++) {
        float bv = wsh[kk * BC + tx + j * 16];
#pragma unroll
        for (int r = 0; r < 4; r++) acc[r][j] = fmaf(av[r], bv, acc[r][j]);
      }
    }
  }
#pragma unroll
  for (int r = 0; r < 4; r++) {
    int row = r0 + ty * 4 + r;
    float dr = dis[row];
#pragma unroll
    for (int j = 0; j < NJ; j++)
      out[(size_t)row * BC + tx + j * 16] = __float2bfloat16(acc[r][j] * dr);
  }
}

// ---------------------------------------------------------------- GEMM layer 2
__global__ __launch_bounds__(256) void gemm2_kernel(
    const unsigned short* __restrict__ A, const float* __restrict__ W,
    const float* __restrict__ sums, const float* __restrict__ g,
    const float* __restrict__ b, const float* __restrict__ dis,
    __hip_bfloat16* __restrict__ out) {
  constexpr int BC = 64, NJ = 4, WF4 = 2;
  __shared__ float xs[64 * 33];
  __shared__ float wsh[32 * BC];
  __shared__ float s_scl[128], s_shf[128];
  int tid = threadIdx.x;
  if (tid < 128) {
    float mean = sums[tid] / (float)kN;
    float var = sums[128 + tid] / (float)kN - mean * mean;
    float inv = rsqrtf(var + kEps);
    float sc = g[tid] * inv;
    s_scl[tid] = sc;
    s_shf[tid] = b[tid] - mean * sc;
  }
  int tx = tid & 15, ty = tid >> 4;
  int r0 = blockIdx.x * 64;
  float acc[4][NJ];
#pragma unroll
  for (int r = 0; r < 4; r++)
#pragma unroll
    for (int j = 0; j < NJ; j++) acc[r][j] = 0.f;

  for (int kb = 0; kb < 128; kb += 32) {
    __syncthreads();
    {
      int row = tid >> 2, kq = tid & 3;
      short8v v8 = *(const short8v*)(A + (size_t)(r0 + row) * 128 + kb + kq * 8);
      int bb = row * 33 + kq * 8;
#pragma unroll
      for (int j = 0; j < 8; j++) {
        int c = kb + kq * 8 + j;
        float v = bf2f((unsigned short)v8[j]);
        xs[bb + j] = fmaxf(0.f, fmaf(v, s_scl[c], s_shf[c]));
      }
    }
#pragma unroll
    for (int q = 0; q < WF4; q++) {
      int f = tid + q * 256;
      int k = f / (BC / 4), cq = f % (BC / 4);
      *(float4*)&wsh[k * BC + cq * 4] =
          *(const float4*)(W + (size_t)(kb + k) * BC + cq * 4);
    }
    __syncthreads();
#pragma unroll
    for (int kk = 0; kk < 32; kk++) {
      float av[4];
#pragma unroll
      for (int r = 0; r < 4; r++) av[r] = xs[(ty * 4 + r) * 33 + kk];
#pragma unroll
      for (int j = 0; j < NJ; j++) {
        float bv = wsh[kk * BC + tx + j * 16];
#pragma unroll
        for (int r = 0; r < 4; r++) acc[r][j] = fmaf(av[r], bv, acc[r][j]);
      }
    }
  }
#pragma unroll
  for (int r = 0; r < 4; r++) {
    int row = r0 + ty * 4 + r;
    float dr = dis[row];
#pragma unroll
    for (int j = 0; j < NJ; j++)
      out[(size_t)row * BC + tx + j * 16] = __float2bfloat16(acc[r][j] * dr);
  }
}

// ---------------------------------------------------------------- aggregation
__global__ __launch_bounds__(256) void agg1_kernel(const unsigned short* __restrict__ hs,
    const int* __restrict__ csr_src, const int* __restrict__ offsets,
    const int* __restrict__ counts, const float* __restrict__ dis,
    unsigned short* __restrict__ t1) {
  int tid = threadIdx.x;
  int wv = tid >> 6, lane = tid & 63;
  int d = blockIdx.x * 4 + wv;
  int g = lane >> 4, l = lane & 15;
  float acc[8];
  if (g == 0) {
    short8v v = *(const short8v*)(hs + (size_t)d * 128 + l * 8);
#pragma unroll
    for (int j = 0; j < 8; j++) acc[j] = bf2f((unsigned short)v[j]);
  } else {
#pragma unroll
    for (int j = 0; j < 8; j++) acc[j] = 0.f;
  }
  int s0 = offsets[d], n = counts[d];
  int i = g;
  for (; i + 4 < n; i += 8) {
    int sa = csr_src[s0 + i];
    int sb = csr_src[s0 + i + 4];
    short8v va = *(const short8v*)(hs + (size_t)sa * 128 + l * 8);
    short8v vb = *(const short8v*)(hs + (size_t)sb * 128 + l * 8);
#pragma unroll
    for (int j = 0; j < 8; j++) acc[j] += bf2f((unsigned short)va[j]);
#pragma unroll
    for (int j = 0; j < 8; j++) acc[j] += bf2f((unsigned short)vb[j]);
  }
  if (i < n) {
    int sa = csr_src[s0 + i];
    short8v va = *(const short8v*)(hs + (size_t)sa * 128 + l * 8);
#pragma unroll
    for (int j = 0; j < 8; j++) acc[j] += bf2f((unsigned short)va[j]);
  }
#pragma unroll
  for (int j = 0; j < 8; j++) {
    acc[j] += __shfl_xor(acc[j], 16, 64);
    acc[j] += __shfl_xor(acc[j], 32, 64);
  }
  if (g == 0) {
    float dd = dis[d];
    short8v o;
#pragma unroll
    for (int j = 0; j < 8; j++) o[j] = (short)f2bf(acc[j] * dd);
    *(short8v*)(t1 + (size_t)d * 128 + l * 8) = o;
  }
}

__global__ __launch_bounds__(256) void agg2_kernel(const unsigned short* __restrict__ hs,
    const int* __restrict__ csr_src, const int* __restrict__ offsets,
    const int* __restrict__ counts, const float* __restrict__ dis,
    float* __restrict__ t2) {
  int tid = threadIdx.x;
  int wv = tid >> 6, lane = tid & 63;
  int d = blockIdx.x * 4 + wv;
  int g = lane >> 3, l = lane & 7;
  float acc[8];
  if (g == 0) {
    short8v v = *(const short8v*)(hs + (size_t)d * 64 + l * 8);
#pragma unroll
    for (int j = 0; j < 8; j++) acc[j] = bf2f((unsigned short)v[j]);
  } else {
#pragma unroll
    for (int j = 0; j < 8; j++) acc[j] = 0.f;
  }
  int s0 = offsets[d], n = counts[d];
  int i = g;
  for (; i + 8 < n; i += 16) {
    int sa = csr_src[s0 + i];
    int sb = csr_src[s0 + i + 8];
    short8v va = *(const short8v*)(hs + (size_t)sa * 64 + l * 8);
    short8v vb = *(const short8v*)(hs + (size_t)sb * 64 + l * 8);
#pragma unroll
    for (int j = 0; j < 8; j++) acc[j] += bf2f((unsigned short)va[j]);
#pragma unroll
    for (int j = 0; j < 8; j++) acc[j] += bf2f((unsigned short)vb[j]);
  }
  if (i < n) {
    int sa = csr_src[s0 + i];
    short8v va = *(const short8v*)(hs + (size_t)sa * 64 + l * 8);
#pragma unroll
    for (int j = 0; j < 8; j++) acc[j] += bf2f((unsigned short)va[j]);
  }
#pragma unroll
  for (int j = 0; j < 8; j++) {
    acc[j] += __shfl_xor(acc[j], 8, 64);
    acc[j] += __shfl_xor(acc[j], 16, 64);
    acc[j] += __shfl_xor(acc[j], 32, 64);
  }
  if (g == 0) {
    float dd = dis[d];
    float* o = t2 + (size_t)d * 64 + l * 8;
    f32x4 o0 = {acc[0] * dd, acc[1] * dd, acc[2] * dd, acc[3] * dd};
    f32x4 o1 = {acc[4] * dd, acc[5] * dd, acc[6] * dd, acc[7] * dd};
    *(f32x4*)o = o0;
    *(f32x4*)(o + 4) = o1;
  }
}

// ---------------------------------------------------------------- BN stats
template <int C, bool BF16>
__global__ __launch_bounds__(256) void stats_kernel(const void* __restrict__ t,
                                                    float* __restrict__ sums) {
  constexpr int RP = 256 / C;
  int c = threadIdx.x % C;
  int rr = threadIdx.x / C;
  float s = 0.f, s2 = 0.f;
  for (int r = blockIdx.x * RP + rr; r < kN; r += gridDim.x * RP) {
    float v;
    if constexpr (BF16) v = bf2f(((const unsigned short*)t)[(size_t)r * C + c]);
    else v = ((const float*)t)[(size_t)r * C + c];
    s += v;
    s2 += v * v;
  }
  atomicAdd(&sums[c], s);
  atomicAdd(&sums[C + c], s2);
}

// ---------------------------------------------------------------- z + heads (fused)
__global__ __launch_bounds__(256) void zheads_kernel(const float* __restrict__ t2,
    const float* __restrict__ sums, const float* __restrict__ gg,
    const float* __restrict__ bb2,
    const float* __restrict__ wbin, const float* __restrict__ bbin,
    const float* __restrict__ wmc, const float* __restrict__ bmc,
    const float* __restrict__ wcont, const float* __restrict__ bcont,
    float* __restrict__ out0, unsigned short* __restrict__ zb) {
  __shared__ float wT[30 * 64];
  __shared__ float bias[32];
  __shared__ float s_scl[64], s_shf[64];
  int tid = threadIdx.x;
  for (int idx = tid; idx < 1920; idx += 256) {
    int j = idx >> 6, k = idx & 63;
    const float* src = (j < 10) ? wbin : (j < 20) ? wmc : wcont;
    wT[idx] = src[k * 10 + (j % 10)];
  }
  if (tid < 30)
    bias[tid] = (tid < 10) ? bbin[tid] : (tid < 20) ? bmc[tid - 10] : bcont[tid - 20];
  if (tid < 64) {
    float mean = sums[tid] / (float)kN;
    float var = sums[64 + tid] / (float)kN - mean * mean;
    float inv = rsqrtf(var + kEps);
    float sc = gg[tid] * inv;
    s_scl[tid] = sc;
    s_shf[tid] = bb2[tid] - mean * sc;
  }
  __syncthreads();
  int n = blockIdx.x * 256 + tid;
  float zr[64];
  const float4* t4 = (const float4*)(t2 + (size_t)n * 64);
#pragma unroll
  for (int q = 0; q < 16; q++) {
    float4 v = t4[q];
    zr[4 * q + 0] = fmaxf(0.f, fmaf(v.x, s_scl[4 * q + 0], s_shf[4 * q + 0]));
    zr[4 * q + 1] = fmaxf(0.f, fmaf(v.y, s_scl[4 * q + 1], s_shf[4 * q + 1]));
    zr[4 * q + 2] = fmaxf(0.f, fmaf(v.z, s_scl[4 * q + 2], s_shf[4 * q + 2]));
    zr[4 * q + 3] = fmaxf(0.f, fmaf(v.w, s_scl[4 * q + 3], s_shf[4 * q + 3]));
  }
  unsigned short* zrow = zb + (size_t)n * 64;
#pragma unroll
  for (int q = 0; q < 8; q++) {
    short8v o;
#pragma unroll
    for (int j = 0; j < 8; j++) o[j] = (short)f2bf(zr[q * 8 + j]);
    *(short8v*)(zrow + q * 8) = o;
  }
  float acc[30];
#pragma unroll
  for (int j = 0; j < 30; j++) {
    float s = bias[j];
#pragma unroll
    for (int kc = 0; kc < 16; kc++) {
      f32x4 wv = *(const f32x4*)&wT[j * 64 + kc * 4];
      s = fmaf(zr[4 * kc + 0], wv.x, s);
      s = fmaf(zr[4 * kc + 1], wv.y, s);
      s = fmaf(zr[4 * kc + 2], wv.z, s);
      s = fmaf(zr[4 * kc + 3], wv.w, s);
    }
    acc[j] = s;
  }
  float* o = out0 + (size_t)n * 30;
#pragma unroll
  for (int j = 0; j < 10; j++) o[j] = 1.f / (1.f + expf(-acc[j]));
  float m1 = fmaxf(fmaxf(acc[10], acc[11]), fmaxf(acc[12], acc[13]));
  float e1[4], s1 = 0.f;
#pragma unroll
  for (int j = 0; j < 4; j++) { e1[j] = expf(acc[10 + j] - m1); s1 += e1[j]; }
#pragma unroll
  for (int j = 0; j < 4; j++) o[10 + j] = e1[j] / s1;
  float m2 = acc[14];
#pragma unroll
  for (int j = 15; j < 20; j++) m2 = fmaxf(m2, acc[j]);
  float e2[6], s2 = 0.f;
#pragma unroll
  for (int j = 0; j < 6; j++) { e2[j] = expf(acc[14 + j] - m2); s2 += e2[j]; }
#pragma unroll
  for (int j = 0; j < 6; j++) o[14 + j] = e2[j] / s2;
#pragma unroll
  for (int j = 0; j < 10; j++) o[20 + j] = acc[20 + j];
}

// ---------------------------------------------------------------- adj + edge (fused, heterogeneous blocks)
// blocks [0,1024): edge-feature MFMA path.
// blocks [1024, 1024+16384): adj = z z^T, R9 128x128 tile, LDS-staged
// coalesced stores; mapping bcol-FAST so concurrent blocks write one
// contiguous 512-row band.
__global__ __launch_bounds__(256) void adjedge_kernel(const short* __restrict__ zb,
    const int* __restrict__ srcs, const int* __restrict__ dsts,
    const short* __restrict__ wfr, const float* __restrict__ be,
    float* __restrict__ adj, float* __restrict__ eout) {
  __shared__ float cs[128 * 132];
  int tid = threadIdx.x;
  int wid = tid >> 6, lane = tid & 63;
  int lr = lane & 15, lg = lane >> 4;

  if (blockIdx.x < 1024) {
    // ---------------- edge path ----------------
    float* es = &cs[wid * 256];
    int gw = blockIdx.x * 4 + wid;       // 4096 waves total
    short8v bfr[4];
#pragma unroll
    for (int f = 0; f < 4; f++)
      bfr[f] = *(const short8v*)(wfr + ((size_t)f * 64 + lane) * 8);
    float bias = be[lr];
    for (int t = 0; t < 8; t++) {
      int e0 = (gw * 8 + t) * 16;
      int se = srcs[e0 + lr], de = dsts[e0 + lr];
      short8v a0 = *(const short8v*)(zb + (size_t)se * 64 + lg * 8);
      short8v a1 = *(const short8v*)(zb + (size_t)se * 64 + 32 + lg * 8);
      short8v a2 = *(const short8v*)(zb + (size_t)de * 64 + lg * 8);
      short8v a3 = *(const short8v*)(zb + (size_t)de * 64 + 32 + lg * 8);
      f32x4 acc = {0.f, 0.f, 0.f, 0.f};
      acc = __builtin_amdgcn_mfma_f32_16x16x32_bf16(a0, bfr[0], acc, 0, 0, 0);
      acc = __builtin_amdgcn_mfma_f32_16x16x32_bf16(a1, bfr[1], acc, 0, 0, 0);
      acc = __builtin_amdgcn_mfma_f32_16x16x32_bf16(a2, bfr[2], acc, 0, 0, 0);
      acc = __builtin_amdgcn_mfma_f32_16x16x32_bf16(a3, bfr[3], acc, 0, 0, 0);
#pragma unroll
      for (int r = 0; r < 4; r++)
        es[(lg * 4 + r) * 16 + lr] = acc[r] + bias;
      f32x4 v = *(const f32x4*)&es[lane * 4];
      *(f32x4*)(eout + (size_t)e0 * 16 + lane * 4) = v;
    }
    return;
  }

  // ---------------- adj path (R9 math; bcol-fast mapping) ----------------
  int bid = blockIdx.x - 1024;
  int bcol = bid & 127;                 // FAST index -> concurrent blocks
  int brow = bid >> 7;                  // share a 512-row output band
  int li0 = (wid >> 1) * 64;
  int lj0 = (wid & 1) * 64;
  int i0 = brow * 128 + li0;
  int j0 = bcol * 128 + lj0;
  short8v a[4][2], b[4][2];
#pragma unroll
  for (int mt = 0; mt < 4; mt++)
#pragma unroll
    for (int ks = 0; ks < 2; ks++)
      a[mt][ks] = *(const short8v*)(zb + (size_t)(i0 + mt * 16 + lr) * 64 + ks * 32 + lg * 8);
#pragma unroll
  for (int nt = 0; nt < 4; nt++)
#pragma unroll
    for (int ks = 0; ks < 2; ks++)
      b[nt][ks] = *(const short8v*)(zb + (size_t)(j0 + nt * 16 + lr) * 64 + ks * 32 + lg * 8);
  f32x4 acc[4][4];
#pragma unroll
  for (int mt = 0; mt < 4; mt++)
#pragma unroll
    for (int nt = 0; nt < 4; nt++) {
      f32x4 zz = {0.f, 0.f, 0.f, 0.f};
      acc[mt][nt] = zz;
    }
#pragma unroll
  for (int ks = 0; ks < 2; ks++)
#pragma unroll
    for (int mt = 0; mt < 4; mt++)
#pragma unroll
      for (int nt = 0; nt < 4; nt++)
        acc[mt][nt] = __builtin_amdgcn_mfma_f32_16x16x32_bf16(a[mt][ks], b[nt][ks],
                                                              acc[mt][nt], 0, 0, 0);
#pragma unroll
  for (int mt = 0; mt < 4; mt++)
#pragma unroll
    for (int nt = 0; nt < 4; nt++)
#pragma unroll
      for (int r = 0; r < 4; r++)
        cs[(li0 + mt * 16 + lg * 4 + r) * 132 + lj0 + nt * 16 + lr] = acc[mt][nt][r];
  __syncthreads();
  int row = tid >> 5;
  int c4 = tid & 31;
  size_t gbase = (size_t)(brow * 128 + row) * kN + bcol * 128 + c4 * 4;
  const float* lbase = &cs[row * 132 + c4 * 4];
#pragma unroll
  for (int it = 0; it < 16; it++) {
    f32x4 v = *(const f32x4*)(lbase + it * 8 * 132);
    *(f32x4*)(adj + gbase + (size_t)it * 8 * kN) = v;
  }
}

// ---------------------------------------------------------------- launch
extern "C" void kernel_launch(void* const* d_in, const int* in_sizes, int n_in,
                              void* d_out, int out_size, void* d_ws, size_t ws_size,
                              hipStream_t stream) {
  const float* x      = (const float*)d_in[0];
  const int*   ei     = (const int*)d_in[1];
  const float* w1     = (const float*)d_in[3];
  const float* bn1_g  = (const float*)d_in[5];
  const float* bn1_b  = (const float*)d_in[6];
  const float* w2     = (const float*)d_in[7];
  const float* bn2_g  = (const float*)d_in[9];
  const float* bn2_b  = (const float*)d_in[10];
  const float* w_bin  = (const float*)d_in[11];
  const float* b_bin  = (const float*)d_in[12];
  const float* w_mc   = (const float*)d_in[13];
  const float* b_mc   = (const float*)d_in[14];
  const float* w_cont = (const float*)d_in[15];
  const float* b_cont = (const float*)d_in[16];
  const float* w_edge = (const float*)d_in[17];
  const float* b_edge = (const float*)d_in[18];

  float* out0 = (float*)d_out;
  float* adj  = out0 + (size_t)kN * 30;
  float* eout = adj + (size_t)kN * kN;

  char* wp = (char*)d_ws;
  auto alloc = [&](size_t bytes) {
    char* p = wp;
    wp += (bytes + 255) & ~(size_t)255;
    return p;
  };
  int*   counts  = (int*)alloc((size_t)kN * 4);
  int*   offsets = (int*)alloc((size_t)kN * 4);
  int*   pos     = (int*)alloc((size_t)kN * 4);
  int*   csr_src = (int*)alloc((size_t)kE * 4);
  float* dis     = (float*)alloc((size_t)kN * 4);
  float* sums1   = (float*)alloc(256 * 4);
  float* sums2   = (float*)alloc(128 * 4);
  unsigned short* hs1 = (unsigned short*)alloc((size_t)kN * 128 * 2);
  unsigned short* t1  = (unsigned short*)alloc((size_t)kN * 128 * 2);
  unsigned short* hs2 = (unsigned short*)alloc((size_t)kN * 64 * 2);
  float* t2      = (float*)alloc((size_t)kN * 64 * 4);
  unsigned short* zb  = (unsigned short*)alloc((size_t)kN * 64 * 2);
  __hip_bfloat16* wfr = (__hip_bfloat16*)alloc(2048 * 2);

  const int* esrc = ei;
  const int* edst = ei + kE;

  zero_kernel<<<dim3(64), dim3(256), 0, stream>>>(counts, sums1, sums2, w_edge, wfr);
  hist_kernel<<<dim3(2048), dim3(256), 0, stream>>>(edst, counts);
  scan_kernel<<<dim3(1), dim3(1024), 0, stream>>>(counts, offsets, pos, dis);
  fill_kernel<<<dim3(2048), dim3(256), 0, stream>>>(esrc, edst, pos, csr_src);

  gemm1_kernel<<<dim3(kN / 64), dim3(256), 0, stream>>>(
      x, w1, dis, (__hip_bfloat16*)hs1);
  agg1_kernel<<<dim3(kN / 4), dim3(256), 0, stream>>>(
      hs1, csr_src, offsets, counts, dis, t1);
  stats_kernel<128, true><<<dim3(256), dim3(256), 0, stream>>>(t1, sums1);

  gemm2_kernel<<<dim3(kN / 64), dim3(256), 0, stream>>>(
      t1, w2, sums1, bn1_g, bn1_b, dis, (__hip_bfloat16*)hs2);
  agg2_kernel<<<dim3(kN / 4), dim3(256), 0, stream>>>(
      hs2, csr_src, offsets, counts, dis, t2);
  stats_kernel<64, false><<<dim3(256), dim3(256), 0, stream>>>(t2, sums2);

  zheads_kernel<<<dim3(kN / 256), dim3(256), 0, stream>>>(
      t2, sums2, bn2_g, bn2_b, w_bin, b_bin, w_mc, b_mc, w_cont, b_cont, out0, zb);

  adjedge_kernel<<<dim3(1024 + 16384), dim3(256), 0, stream>>>(
      (const short*)zb, esrc, edst, (const short*)wfr, b_edge, adj, eout);
}

// Round 13
// 419.738 us; speedup vs baseline: 1.2983x; 1.0061x over previous
//
#include <hip/hip_runtime.h>
#include <hip/hip_bf16.h>
#include <math.h>

// GAE on MI355X. N=16384 nodes, E=524288 edges.
// R13: front-chain shortening. gemm1 no longer applies dis (deferred into
// agg1: t1[d] = dis[d]*(sum dis[s]*h[s] + dis[d]*h[d])), which breaks its
// dependency on scan -> gemm1 fused into the hist launch as heterogeneous
// blocks (0-2047 hist, 2048-2303 gemm1). 11 launches. adj/edge = R12.

constexpr int kN = 16384;
constexpr int kE = 524288;
constexpr float kEps = 1e-5f;

typedef __attribute__((ext_vector_type(8))) short short8v;   // 8 x bf16
typedef __attribute__((ext_vector_type(4))) float f32x4;

__device__ inline float bf2f(unsigned short u) {
  return __uint_as_float(((unsigned)u) << 16);
}
__device__ inline unsigned short f2bf(float f) {  // RNE
  unsigned u = __float_as_uint(f);
  return (unsigned short)((u + 0x7fff + ((u >> 16) & 1)) >> 16);
}

// ---------------------------------------------------------------- utility
__global__ void zero_kernel(int* counts, float* sums1, float* sums2,
                            const float* __restrict__ we, __hip_bfloat16* wfr) {
  int i = blockIdx.x * 256 + threadIdx.x;
  if (i < kN) counts[i] = 0;
  if (i < 256) sums1[i] = 0.f;
  if (i < 128) sums2[i] = 0.f;
  if (i < 2048) {
    int f = i >> 9, l = (i >> 3) & 63, j = i & 7;
    int lr = l & 15, lg = l >> 4;
    int krow = f * 32 + lg * 8 + j;
    wfr[i] = __float2bfloat16(we[krow * 16 + lr]);
  }
}

// ---------------------------------------------------------------- hist + gemm1 (fused)
// blocks [0,2048): histogram of dst. blocks [2048,2304): h = x@W1 (bf16, no
// dis scale - deferred to agg1).
__global__ __launch_bounds__(256) void histgemm1_kernel(
    const int* __restrict__ dst, int* __restrict__ counts,
    const float* __restrict__ A, const float* __restrict__ W,
    __hip_bfloat16* __restrict__ out) {
  if (blockIdx.x < 2048) {
    int e = blockIdx.x * 256 + threadIdx.x;
    atomicAdd(&counts[dst[e]], 1);
    return;
  }
  constexpr int BC = 128, NJ = 8, WF4 = 4;
  __shared__ float xs[64 * 33];
  __shared__ float wsh[32 * BC];
  int tid = threadIdx.x;
  int tx = tid & 15, ty = tid >> 4;
  int r0 = (blockIdx.x - 2048) * 64;
  float acc[4][NJ];
#pragma unroll
  for (int r = 0; r < 4; r++)
#pragma unroll
    for (int j = 0; j < NJ; j++) acc[r][j] = 0.f;

  for (int kb = 0; kb < 128; kb += 32) {
    __syncthreads();
#pragma unroll
    for (int q = 0; q < 2; q++) {
      int f = tid + q * 256;
      int row = f >> 3, kq = f & 7;
      float4 v = *(const float4*)(A + (size_t)(r0 + row) * 128 + kb + kq * 4);
      int bb = row * 33 + kq * 4;
      xs[bb + 0] = v.x; xs[bb + 1] = v.y; xs[bb + 2] = v.z; xs[bb + 3] = v.w;
    }
#pragma unroll
    for (int q = 0; q < WF4; q++) {
      int f = tid + q * 256;
      int k = f / (BC / 4), cq = f % (BC / 4);
      *(float4*)&wsh[k * BC + cq * 4] =
          *(const float4*)(W + (size_t)(kb + k) * BC + cq * 4);
    }
    __syncthreads();
#pragma unroll
    for (int kk = 0; kk < 32; kk++) {
      float av[4];
#pragma unroll
      for (int r = 0; r < 4; r++) av[r] = xs[(ty * 4 + r) * 33 + kk];
#pragma unroll
      for (int j = 0; j < NJ; j++) {
        float bv = wsh[kk * BC + tx + j * 16];
#pragma unroll
        for (int r = 0; r < 4; r++) acc[r][j] = fmaf(av[r], bv, acc[r][j]);
      }
    }
  }
#pragma unroll
  for (int r = 0; r < 4; r++) {
    int row = r0 + ty * 4 + r;
#pragma unroll
    for (int j = 0; j < NJ; j++)
      out[(size_t)row * BC + tx + j * 16] = __float2bfloat16(acc[r][j]);
  }
}

__global__ __launch_bounds__(1024) void scan_kernel(const int* __restrict__ counts,
    int* __restrict__ offsets, int* __restrict__ pos, float* __restrict__ dis) {
  __shared__ int wave_tot[16];
  int tid = threadIdx.x;
  int base = tid * 16;
  int loc[16];
  int s = 0;
#pragma unroll
  for (int i = 0; i < 16; i++) { loc[i] = s; s += counts[base + i]; }
  int lane = tid & 63, wv = tid >> 6;
  int incl = s;
#pragma unroll
  for (int d = 1; d < 64; d <<= 1) {
    int v = __shfl_up(incl, d, 64);
    if (lane >= d) incl += v;
  }
  if (lane == 63) wave_tot[wv] = incl;
  __syncthreads();
  int woff = 0;
  for (int i = 0; i < wv; i++) woff += wave_tot[i];
  int excl = woff + incl - s;
#pragma unroll
  for (int i = 0; i < 16; i++) {
    int o = excl + loc[i];
    offsets[base + i] = o;
    pos[base + i] = o;
    dis[base + i] = rsqrtf((float)counts[base + i] + 1.0f);  // +1 self-loop
  }
}

__global__ void fill_kernel(const int* __restrict__ src, const int* __restrict__ dst,
                            int* __restrict__ pos, int* __restrict__ csr_src) {
  int e = blockIdx.x * 256 + threadIdx.x;
  if (e < kE) {
    int d = dst[e];
    int p = atomicAdd(&pos[d], 1);
    csr_src[p] = src[e];
  }
}

// ---------------------------------------------------------------- GEMM layer 2
__global__ __launch_bounds__(256) void gemm2_kernel(
    const unsigned short* __restrict__ A, const float* __restrict__ W,
    const float* __restrict__ sums, const float* __restrict__ g,
    const float* __restrict__ b, const float* __restrict__ dis,
    __hip_bfloat16* __restrict__ out) {
  constexpr int BC = 64, NJ = 4, WF4 = 2;
  __shared__ float xs[64 * 33];
  __shared__ float wsh[32 * BC];
  __shared__ float s_scl[128], s_shf[128];
  int tid = threadIdx.x;
  if (tid < 128) {
    float mean = sums[tid] / (float)kN;
    float var = sums[128 + tid] / (float)kN - mean * mean;
    float inv = rsqrtf(var + kEps);
    float sc = g[tid] * inv;
    s_scl[tid] = sc;
    s_shf[tid] = b[tid] - mean * sc;
  }
  int tx = tid & 15, ty = tid >> 4;
  int r0 = blockIdx.x * 64;
  float acc[4][NJ];
#pragma unroll
  for (int r = 0; r < 4; r++)
#pragma unroll
    for (int j = 0; j < NJ; j++) acc[r][j] = 0.f;

  for (int kb = 0; kb < 128; kb += 32) {
    __syncthreads();
    {
      int row = tid >> 2, kq = tid & 3;
      short8v v8 = *(const short8v*)(A + (size_t)(r0 + row) * 128 + kb + kq * 8);
      int bb = row * 33 + kq * 8;
#pragma unroll
      for (int j = 0; j < 8; j++) {
        int c = kb + kq * 8 + j;
        float v = bf2f((unsigned short)v8[j]);
        xs[bb + j] = fmaxf(0.f, fmaf(v, s_scl[c], s_shf[c]));
      }
    }
#pragma unroll
    for (int q = 0; q < WF4; q++) {
      int f = tid + q * 256;
      int k = f / (BC / 4), cq = f % (BC / 4);
      *(float4*)&wsh[k * BC + cq * 4] =
          *(const float4*)(W + (size_t)(kb + k) * BC + cq * 4);
    }
    __syncthreads();
#pragma unroll
    for (int kk = 0; kk < 32; kk++) {
      float av[4];
#pragma unroll
      for (int r = 0; r < 4; r++) av[r] = xs[(ty * 4 + r) * 33 + kk];
#pragma unroll
      for (int j = 0; j < NJ; j++) {
        float bv = wsh[kk * BC + tx + j * 16];
#pragma unroll
        for (int r = 0; r < 4; r++) acc[r][j] = fmaf(av[r], bv, acc[r][j]);
      }
    }
  }
#pragma unroll
  for (int r = 0; r < 4; r++) {
    int row = r0 + ty * 4 + r;
    float dr = dis[row];
#pragma unroll
    for (int j = 0; j < NJ; j++)
      out[(size_t)row * BC + tx + j * 16] = __float2bfloat16(acc[r][j] * dr);
  }
}

// ---------------------------------------------------------------- aggregation
// agg1: h is UNscaled; apply dis[s] per gathered row and dis[d] twice for
// the self-loop: t1[d] = dis[d]*(dis[d]*h[d] + sum dis[s]*h[s]).
__global__ __launch_bounds__(256) void agg1_kernel(const unsigned short* __restrict__ hs,
    const int* __restrict__ csr_src, const int* __restrict__ offsets,
    const int* __restrict__ counts, const float* __restrict__ dis,
    unsigned short* __restrict__ t1) {
  int tid = threadIdx.x;
  int wv = tid >> 6, lane = tid & 63;
  int d = blockIdx.x * 4 + wv;
  int g = lane >> 4, l = lane & 15;
  float dd = dis[d];
  float acc[8];
  if (g == 0) {
    short8v v = *(const short8v*)(hs + (size_t)d * 128 + l * 8);
#pragma unroll
    for (int j = 0; j < 8; j++) acc[j] = bf2f((unsigned short)v[j]) * dd;
  } else {
#pragma unroll
    for (int j = 0; j < 8; j++) acc[j] = 0.f;
  }
  int s0 = offsets[d], n = counts[d];
  int i = g;
  for (; i + 4 < n; i += 8) {
    int sa = csr_src[s0 + i];
    int sb = csr_src[s0 + i + 4];
    float da = dis[sa], db = dis[sb];
    short8v va = *(const short8v*)(hs + (size_t)sa * 128 + l * 8);
    short8v vb = *(const short8v*)(hs + (size_t)sb * 128 + l * 8);
#pragma unroll
    for (int j = 0; j < 8; j++) acc[j] = fmaf(bf2f((unsigned short)va[j]), da, acc[j]);
#pragma unroll
    for (int j = 0; j < 8; j++) acc[j] = fmaf(bf2f((unsigned short)vb[j]), db, acc[j]);
  }
  if (i < n) {
    int sa = csr_src[s0 + i];
    float da = dis[sa];
    short8v va = *(const short8v*)(hs + (size_t)sa * 128 + l * 8);
#pragma unroll
    for (int j = 0; j < 8; j++) acc[j] = fmaf(bf2f((unsigned short)va[j]), da, acc[j]);
  }
#pragma unroll
  for (int j = 0; j < 8; j++) {
    acc[j] += __shfl_xor(acc[j], 16, 64);
    acc[j] += __shfl_xor(acc[j], 32, 64);
  }
  if (g == 0) {
    short8v o;
#pragma unroll
    for (int j = 0; j < 8; j++) o[j] = (short)f2bf(acc[j] * dd);
    *(short8v*)(t1 + (size_t)d * 128 + l * 8) = o;
  }
}

__global__ __launch_bounds__(256) void agg2_kernel(const unsigned short* __restrict__ hs,
    const int* __restrict__ csr_src, const int* __restrict__ offsets,
    const int* __restrict__ counts, const float* __restrict__ dis,
    float* __restrict__ t2) {
  int tid = threadIdx.x;
  int wv = tid >> 6, lane = tid & 63;
  int d = blockIdx.x * 4 + wv;
  int g = lane >> 3, l = lane & 7;
  float acc[8];
  if (g == 0) {
    short8v v = *(const short8v*)(hs + (size_t)d * 64 + l * 8);
#pragma unroll
    for (int j = 0; j < 8; j++) acc[j] = bf2f((unsigned short)v[j]);
  } else {
#pragma unroll
    for (int j = 0; j < 8; j++) acc[j] = 0.f;
  }
  int s0 = offsets[d], n = counts[d];
  int i = g;
  for (; i + 8 < n; i += 16) {
    int sa = csr_src[s0 + i];
    int sb = csr_src[s0 + i + 8];
    short8v va = *(const short8v*)(hs + (size_t)sa * 64 + l * 8);
    short8v vb = *(const short8v*)(hs + (size_t)sb * 64 + l * 8);
#pragma unroll
    for (int j = 0; j < 8; j++) acc[j] += bf2f((unsigned short)va[j]);
#pragma unroll
    for (int j = 0; j < 8; j++) acc[j] += bf2f((unsigned short)vb[j]);
  }
  if (i < n) {
    int sa = csr_src[s0 + i];
    short8v va = *(const short8v*)(hs + (size_t)sa * 64 + l * 8);
#pragma unroll
    for (int j = 0; j < 8; j++) acc[j] += bf2f((unsigned short)va[j]);
  }
#pragma unroll
  for (int j = 0; j < 8; j++) {
    acc[j] += __shfl_xor(acc[j], 8, 64);
    acc[j] += __shfl_xor(acc[j], 16, 64);
    acc[j] += __shfl_xor(acc[j], 32, 64);
  }
  if (g == 0) {
    float dd = dis[d];
    float* o = t2 + (size_t)d * 64 + l * 8;
    f32x4 o0 = {acc[0] * dd, acc[1] * dd, acc[2] * dd, acc[3] * dd};
    f32x4 o1 = {acc[4] * dd, acc[5] * dd, acc[6] * dd, acc[7] * dd};
    *(f32x4*)o = o0;
    *(f32x4*)(o + 4) = o1;
  }
}

// ---------------------------------------------------------------- BN stats
template <int C, bool BF16>
__global__ __launch_bounds__(256) void stats_kernel(const void* __restrict__ t,
                                                    float* __restrict__ sums) {
  constexpr int RP = 256 / C;
  int c = threadIdx.x % C;
  int rr = threadIdx.x / C;
  float s = 0.f, s2 = 0.f;
  for (int r = blockIdx.x * RP + rr; r < kN; r += gridDim.x * RP) {
    float v;
    if constexpr (BF16) v = bf2f(((const unsigned short*)t)[(size_t)r * C + c]);
    else v = ((const float*)t)[(size_t)r * C + c];
    s += v;
    s2 += v * v;
  }
  atomicAdd(&sums[c], s);
  atomicAdd(&sums[C + c], s2);
}

// ---------------------------------------------------------------- z + heads (fused)
__global__ __launch_bounds__(256) void zheads_kernel(const float* __restrict__ t2,
    const float* __restrict__ sums, const float* __restrict__ gg,
    const float* __restrict__ bb2,
    const float* __restrict__ wbin, const float* __restrict__ bbin,
    const float* __restrict__ wmc, const float* __restrict__ bmc,
    const float* __restrict__ wcont, const float* __restrict__ bcont,
    float* __restrict__ out0, unsigned short* __restrict__ zb) {
  __shared__ float wT[30 * 64];
  __shared__ float bias[32];
  __shared__ float s_scl[64], s_shf[64];
  int tid = threadIdx.x;
  for (int idx = tid; idx < 1920; idx += 256) {
    int j = idx >> 6, k = idx & 63;
    const float* src = (j < 10) ? wbin : (j < 20) ? wmc : wcont;
    wT[idx] = src[k * 10 + (j % 10)];
  }
  if (tid < 30)
    bias[tid] = (tid < 10) ? bbin[tid] : (tid < 20) ? bmc[tid - 10] : bcont[tid - 20];
  if (tid < 64) {
    float mean = sums[tid] / (float)kN;
    float var = sums[64 + tid] / (float)kN - mean * mean;
    float inv = rsqrtf(var + kEps);
    float sc = gg[tid] * inv;
    s_scl[tid] = sc;
    s_shf[tid] = bb2[tid] - mean * sc;
  }
  __syncthreads();
  int n = blockIdx.x * 256 + tid;
  float zr[64];
  const float4* t4 = (const float4*)(t2 + (size_t)n * 64);
#pragma unroll
  for (int q = 0; q < 16; q++) {
    float4 v = t4[q];
    zr[4 * q + 0] = fmaxf(0.f, fmaf(v.x, s_scl[4 * q + 0], s_shf[4 * q + 0]));
    zr[4 * q + 1] = fmaxf(0.f, fmaf(v.y, s_scl[4 * q + 1], s_shf[4 * q + 1]));
    zr[4 * q + 2] = fmaxf(0.f, fmaf(v.z, s_scl[4 * q + 2], s_shf[4 * q + 2]));
    zr[4 * q + 3] = fmaxf(0.f, fmaf(v.w, s_scl[4 * q + 3], s_shf[4 * q + 3]));
  }
  unsigned short* zrow = zb + (size_t)n * 64;
#pragma unroll
  for (int q = 0; q < 8; q++) {
    short8v o;
#pragma unroll
    for (int j = 0; j < 8; j++) o[j] = (short)f2bf(zr[q * 8 + j]);
    *(short8v*)(zrow + q * 8) = o;
  }
  float acc[30];
#pragma unroll
  for (int j = 0; j < 30; j++) {
    float s = bias[j];
#pragma unroll
    for (int kc = 0; kc < 16; kc++) {
      f32x4 wv = *(const f32x4*)&wT[j * 64 + kc * 4];
      s = fmaf(zr[4 * kc + 0], wv.x, s);
      s = fmaf(zr[4 * kc + 1], wv.y, s);
      s = fmaf(zr[4 * kc + 2], wv.z, s);
      s = fmaf(zr[4 * kc + 3], wv.w, s);
    }
    acc[j] = s;
  }
  float* o = out0 + (size_t)n * 30;
#pragma unroll
  for (int j = 0; j < 10; j++) o[j] = 1.f / (1.f + expf(-acc[j]));
  float m1 = fmaxf(fmaxf(acc[10], acc[11]), fmaxf(acc[12], acc[13]));
  float e1[4], s1 = 0.f;
#pragma unroll
  for (int j = 0; j < 4; j++) { e1[j] = expf(acc[10 + j] - m1); s1 += e1[j]; }
#pragma unroll
  for (int j = 0; j < 4; j++) o[10 + j] = e1[j] / s1;
  float m2 = acc[14];
#pragma unroll
  for (int j = 15; j < 20; j++) m2 = fmaxf(m2, acc[j]);
  float e2[6], s2 = 0.f;
#pragma unroll
  for (int j = 0; j < 6; j++) { e2[j] = expf(acc[14 + j] - m2); s2 += e2[j]; }
#pragma unroll
  for (int j = 0; j < 6; j++) o[14 + j] = e2[j] / s2;
#pragma unroll
  for (int j = 0; j < 10; j++) o[20 + j] = acc[20 + j];
}

// ---------------------------------------------------------------- adj + edge (fused, heterogeneous blocks)
__global__ __launch_bounds__(256) void adjedge_kernel(const short* __restrict__ zb,
    const int* __restrict__ srcs, const int* __restrict__ dsts,
    const short* __restrict__ wfr, const float* __restrict__ be,
    float* __restrict__ adj, float* __restrict__ eout) {
  __shared__ float cs[128 * 132];
  int tid = threadIdx.x;
  int wid = tid >> 6, lane = tid & 63;
  int lr = lane & 15, lg = lane >> 4;

  if (blockIdx.x < 1024) {
    // ---------------- edge path ----------------
    float* es = &cs[wid * 256];
    int gw = blockIdx.x * 4 + wid;       // 4096 waves total
    short8v bfr[4];
#pragma unroll
    for (int f = 0; f < 4; f++)
      bfr[f] = *(const short8v*)(wfr + ((size_t)f * 64 + lane) * 8);
    float bias = be[lr];
    for (int t = 0; t < 8; t++) {
      int e0 = (gw * 8 + t) * 16;
      int se = srcs[e0 + lr], de = dsts[e0 + lr];
      short8v a0 = *(const short8v*)(zb + (size_t)se * 64 + lg * 8);
      short8v a1 = *(const short8v*)(zb + (size_t)se * 64 + 32 + lg * 8);
      short8v a2 = *(const short8v*)(zb + (size_t)de * 64 + lg * 8);
      short8v a3 = *(const short8v*)(zb + (size_t)de * 64 + 32 + lg * 8);
      f32x4 acc = {0.f, 0.f, 0.f, 0.f};
      acc = __builtin_amdgcn_mfma_f32_16x16x32_bf16(a0, bfr[0], acc, 0, 0, 0);
      acc = __builtin_amdgcn_mfma_f32_16x16x32_bf16(a1, bfr[1], acc, 0, 0, 0);
      acc = __builtin_amdgcn_mfma_f32_16x16x32_bf16(a2, bfr[2], acc, 0, 0, 0);
      acc = __builtin_amdgcn_mfma_f32_16x16x32_bf16(a3, bfr[3], acc, 0, 0, 0);
#pragma unroll
      for (int r = 0; r < 4; r++)
        es[(lg * 4 + r) * 16 + lr] = acc[r] + bias;
      f32x4 v = *(const f32x4*)&es[lane * 4];
      *(f32x4*)(eout + (size_t)e0 * 16 + lane * 4) = v;
    }
    return;
  }

  // ---------------- adj path (bcol-fast mapping) ----------------
  int bid = blockIdx.x - 1024;
  int bcol = bid & 127;
  int brow = bid >> 7;
  int li0 = (wid >> 1) * 64;
  int lj0 = (wid & 1) * 64;
  int i0 = brow * 128 + li0;
  int j0 = bcol * 128 + lj0;
  short8v a[4][2], b[4][2];
#pragma unroll
  for (int mt = 0; mt < 4; mt++)
#pragma unroll
    for (int ks = 0; ks < 2; ks++)
      a[mt][ks] = *(const short8v*)(zb + (size_t)(i0 + mt * 16 + lr) * 64 + ks * 32 + lg * 8);
#pragma unroll
  for (int nt = 0; nt < 4; nt++)
#pragma unroll
    for (int ks = 0; ks < 2; ks++)
      b[nt][ks] = *(const short8v*)(zb + (size_t)(j0 + nt * 16 + lr) * 64 + ks * 32 + lg * 8);
  f32x4 acc[4][4];
#pragma unroll
  for (int mt = 0; mt < 4; mt++)
#pragma unroll
    for (int nt = 0; nt < 4; nt++) {
      f32x4 zz = {0.f, 0.f, 0.f, 0.f};
      acc[mt][nt] = zz;
    }
#pragma unroll
  for (int ks = 0; ks < 2; ks++)
#pragma unroll
    for (int mt = 0; mt < 4; mt++)
#pragma unroll
      for (int nt = 0; nt < 4; nt++)
        acc[mt][nt] = __builtin_amdgcn_mfma_f32_16x16x32_bf16(a[mt][ks], b[nt][ks],
                                                              acc[mt][nt], 0, 0, 0);
#pragma unroll
  for (int mt = 0; mt < 4; mt++)
#pragma unroll
    for (int nt = 0; nt < 4; nt++)
#pragma unroll
      for (int r = 0; r < 4; r++)
        cs[(li0 + mt * 16 + lg * 4 + r) * 132 + lj0 + nt * 16 + lr] = acc[mt][nt][r];
  __syncthreads();
  int row = tid >> 5;
  int c4 = tid & 31;
  size_t gbase = (size_t)(brow * 128 + row) * kN + bcol * 128 + c4 * 4;
  const float* lbase = &cs[row * 132 + c4 * 4];
#pragma unroll
  for (int it = 0; it < 16; it++) {
    f32x4 v = *(const f32x4*)(lbase + it * 8 * 132);
    *(f32x4*)(adj + gbase + (size_t)it * 8 * kN) = v;
  }
}

// ---------------------------------------------------------------- launch
extern "C" void kernel_launch(void* const* d_in, const int* in_sizes, int n_in,
                              void* d_out, int out_size, void* d_ws, size_t ws_size,
                              hipStream_t stream) {
  const float* x      = (const float*)d_in[0];
  const int*   ei     = (const int*)d_in[1];
  const float* w1     = (const float*)d_in[3];
  const float* bn1_g  = (const float*)d_in[5];
  const float* bn1_b  = (const float*)d_in[6];
  const float* w2     = (const float*)d_in[7];
  const float* bn2_g  = (const float*)d_in[9];
  const float* bn2_b  = (const float*)d_in[10];
  const float* w_bin  = (const float*)d_in[11];
  const float* b_bin  = (const float*)d_in[12];
  const float* w_mc   = (const float*)d_in[13];
  const float* b_mc   = (const float*)d_in[14];
  const float* w_cont = (const float*)d_in[15];
  const float* b_cont = (const float*)d_in[16];
  const float* w_edge = (const float*)d_in[17];
  const float* b_edge = (const float*)d_in[18];

  float* out0 = (float*)d_out;
  float* adj  = out0 + (size_t)kN * 30;
  float* eout = adj + (size_t)kN * kN;

  char* wp = (char*)d_ws;
  auto alloc = [&](size_t bytes) {
    char* p = wp;
    wp += (bytes + 255) & ~(size_t)255;
    return p;
  };
  int*   counts  = (int*)alloc((size_t)kN * 4);
  int*   offsets = (int*)alloc((size_t)kN * 4);
  int*   pos     = (int*)alloc((size_t)kN * 4);
  int*   csr_src = (int*)alloc((size_t)kE * 4);
  float* dis     = (float*)alloc((size_t)kN * 4);
  float* sums1   = (float*)alloc(256 * 4);
  float* sums2   = (float*)alloc(128 * 4);
  unsigned short* hs1 = (unsigned short*)alloc((size_t)kN * 128 * 2);
  unsigned short* t1  = (unsigned short*)alloc((size_t)kN * 128 * 2);
  unsigned short* hs2 = (unsigned short*)alloc((size_t)kN * 64 * 2);
  float* t2      = (float*)alloc((size_t)kN * 64 * 4);
  unsigned short* zb  = (unsigned short*)alloc((size_t)kN * 64 * 2);
  __hip_bfloat16* wfr = (__hip_bfloat16*)alloc(2048 * 2);

  const int* esrc = ei;
  const int* edst = ei + kE;

  zero_kernel<<<dim3(64), dim3(256), 0, stream>>>(counts, sums1, sums2, w_edge, wfr);
  histgemm1_kernel<<<dim3(2048 + 256), dim3(256), 0, stream>>>(
      edst, counts, x, w1, (__hip_bfloat16*)hs1);
  scan_kernel<<<dim3(1), dim3(1024), 0, stream>>>(counts, offsets, pos, dis);
  fill_kernel<<<dim3(2048), dim3(256), 0, stream>>>(esrc, edst, pos, csr_src);

  agg1_kernel<<<dim3(kN / 4), dim3(256), 0, stream>>>(
      hs1, csr_src, offsets, counts, dis, t1);
  stats_kernel<128, true><<<dim3(256), dim3(256), 0, stream>>>(t1, sums1);

  gemm2_kernel<<<dim3(kN / 64), dim3(256), 0, stream>>>(
      t1, w2, sums1, bn1_g, bn1_b, dis, (__hip_bfloat16*)hs2);
  agg2_kernel<<<dim3(kN / 4), dim3(256), 0, stream>>>(
      hs2, csr_src, offsets, counts, dis, t2);
  stats_kernel<64, false><<<dim3(256), dim3(256), 0, stream>>>(t2, sums2);

  zheads_kernel<<<dim3(kN / 256), dim3(256), 0, stream>>>(
      t2, sums2, bn2_g, bn2_b, w_bin, b_bin, w_mc, b_mc, w_cont, b_cont, out0, zb);

  adjedge_kernel<<<dim3(1024 + 16384), dim3(256), 0, stream>>>(
      (const short*)zb, esrc, edst, (const short*)wfr, b_edge, adj, eout);
}

// Round 14
// 393.347 us; speedup vs baseline: 1.3854x; 1.0671x over previous
//
#include <hip/hip_runtime.h>
#include <hip/hip_bf16.h>
#include <math.h>

// GAE on MI355X. N=16384 nodes, E=524288 edges.
// R14: adj path to 3 blocks/CU. R9/R13 adj was VGPR-limited (~150 VGPR -> 8
// waves/CU = 2 blocks) AND LDS-limited (67.6 KB). Fix both: launch_bounds
// (256,3) caps at ~170 VGPR (fits existing body, no spill) and the C-tile
// write-out is staged in two 64-row chunks (LDS 33.8 KB < 53 KB). Identical
// math. Rest identical to R13.

constexpr int kN = 16384;
constexpr int kE = 524288;
constexpr float kEps = 1e-5f;

typedef __attribute__((ext_vector_type(8))) short short8v;   // 8 x bf16
typedef __attribute__((ext_vector_type(4))) float f32x4;

__device__ inline float bf2f(unsigned short u) {
  return __uint_as_float(((unsigned)u) << 16);
}
__device__ inline unsigned short f2bf(float f) {  // RNE
  unsigned u = __float_as_uint(f);
  return (unsigned short)((u + 0x7fff + ((u >> 16) & 1)) >> 16);
}

// ---------------------------------------------------------------- utility
__global__ void zero_kernel(int* counts, float* sums1, float* sums2,
                            const float* __restrict__ we, __hip_bfloat16* wfr) {
  int i = blockIdx.x * 256 + threadIdx.x;
  if (i < kN) counts[i] = 0;
  if (i < 256) sums1[i] = 0.f;
  if (i < 128) sums2[i] = 0.f;
  if (i < 2048) {
    int f = i >> 9, l = (i >> 3) & 63, j = i & 7;
    int lr = l & 15, lg = l >> 4;
    int krow = f * 32 + lg * 8 + j;
    wfr[i] = __float2bfloat16(we[krow * 16 + lr]);
  }
}

// ---------------------------------------------------------------- hist + gemm1 (fused)
__global__ __launch_bounds__(256) void histgemm1_kernel(
    const int* __restrict__ dst, int* __restrict__ counts,
    const float* __restrict__ A, const float* __restrict__ W,
    __hip_bfloat16* __restrict__ out) {
  if (blockIdx.x < 2048) {
    int e = blockIdx.x * 256 + threadIdx.x;
    atomicAdd(&counts[dst[e]], 1);
    return;
  }
  constexpr int BC = 128, NJ = 8, WF4 = 4;
  __shared__ float xs[64 * 33];
  __shared__ float wsh[32 * BC];
  int tid = threadIdx.x;
  int tx = tid & 15, ty = tid >> 4;
  int r0 = (blockIdx.x - 2048) * 64;
  float acc[4][NJ];
#pragma unroll
  for (int r = 0; r < 4; r++)
#pragma unroll
    for (int j = 0; j < NJ; j++) acc[r][j] = 0.f;

  for (int kb = 0; kb < 128; kb += 32) {
    __syncthreads();
#pragma unroll
    for (int q = 0; q < 2; q++) {
      int f = tid + q * 256;
      int row = f >> 3, kq = f & 7;
      float4 v = *(const float4*)(A + (size_t)(r0 + row) * 128 + kb + kq * 4);
      int bb = row * 33 + kq * 4;
      xs[bb + 0] = v.x; xs[bb + 1] = v.y; xs[bb + 2] = v.z; xs[bb + 3] = v.w;
    }
#pragma unroll
    for (int q = 0; q < WF4; q++) {
      int f = tid + q * 256;
      int k = f / (BC / 4), cq = f % (BC / 4);
      *(float4*)&wsh[k * BC + cq * 4] =
          *(const float4*)(W + (size_t)(kb + k) * BC + cq * 4);
    }
    __syncthreads();
#pragma unroll
    for (int kk = 0; kk < 32; kk++) {
      float av[4];
#pragma unroll
      for (int r = 0; r < 4; r++) av[r] = xs[(ty * 4 + r) * 33 + kk];
#pragma unroll
      for (int j = 0; j < NJ; j++) {
        float bv = wsh[kk * BC + tx + j * 16];
#pragma unroll
        for (int r = 0; r < 4; r++) acc[r][j] = fmaf(av[r], bv, acc[r][j]);
      }
    }
  }
#pragma unroll
  for (int r = 0; r < 4; r++) {
    int row = r0 + ty * 4 + r;
#pragma unroll
    for (int j = 0; j < NJ; j++)
      out[(size_t)row * BC + tx + j * 16] = __float2bfloat16(acc[r][j]);
  }
}

__global__ __launch_bounds__(1024) void scan_kernel(const int* __restrict__ counts,
    int* __restrict__ offsets, int* __restrict__ pos, float* __restrict__ dis) {
  __shared__ int wave_tot[16];
  int tid = threadIdx.x;
  int base = tid * 16;
  int loc[16];
  int s = 0;
#pragma unroll
  for (int i = 0; i < 16; i++) { loc[i] = s; s += counts[base + i]; }
  int lane = tid & 63, wv = tid >> 6;
  int incl = s;
#pragma unroll
  for (int d = 1; d < 64; d <<= 1) {
    int v = __shfl_up(incl, d, 64);
    if (lane >= d) incl += v;
  }
  if (lane == 63) wave_tot[wv] = incl;
  __syncthreads();
  int woff = 0;
  for (int i = 0; i < wv; i++) woff += wave_tot[i];
  int excl = woff + incl - s;
#pragma unroll
  for (int i = 0; i < 16; i++) {
    int o = excl + loc[i];
    offsets[base + i] = o;
    pos[base + i] = o;
    dis[base + i] = rsqrtf((float)counts[base + i] + 1.0f);  // +1 self-loop
  }
}

__global__ void fill_kernel(const int* __restrict__ src, const int* __restrict__ dst,
                            int* __restrict__ pos, int* __restrict__ csr_src) {
  int e = blockIdx.x * 256 + threadIdx.x;
  if (e < kE) {
    int d = dst[e];
    int p = atomicAdd(&pos[d], 1);
    csr_src[p] = src[e];
  }
}

// ---------------------------------------------------------------- GEMM layer 2
__global__ __launch_bounds__(256) void gemm2_kernel(
    const unsigned short* __restrict__ A, const float* __restrict__ W,
    const float* __restrict__ sums, const float* __restrict__ g,
    const float* __restrict__ b, const float* __restrict__ dis,
    __hip_bfloat16* __restrict__ out) {
  constexpr int BC = 64, NJ = 4, WF4 = 2;
  __shared__ float xs[64 * 33];
  __shared__ float wsh[32 * BC];
  __shared__ float s_scl[128], s_shf[128];
  int tid = threadIdx.x;
  if (tid < 128) {
    float mean = sums[tid] / (float)kN;
    float var = sums[128 + tid] / (float)kN - mean * mean;
    float inv = rsqrtf(var + kEps);
    float sc = g[tid] * inv;
    s_scl[tid] = sc;
    s_shf[tid] = b[tid] - mean * sc;
  }
  int tx = tid & 15, ty = tid >> 4;
  int r0 = blockIdx.x * 64;
  float acc[4][NJ];
#pragma unroll
  for (int r = 0; r < 4; r++)
#pragma unroll
    for (int j = 0; j < NJ; j++) acc[r][j] = 0.f;

  for (int kb = 0; kb < 128; kb += 32) {
    __syncthreads();
    {
      int row = tid >> 2, kq = tid & 3;
      short8v v8 = *(const short8v*)(A + (size_t)(r0 + row) * 128 + kb + kq * 8);
      int bb = row * 33 + kq * 8;
#pragma unroll
      for (int j = 0; j < 8; j++) {
        int c = kb + kq * 8 + j;
        float v = bf2f((unsigned short)v8[j]);
        xs[bb + j] = fmaxf(0.f, fmaf(v, s_scl[c], s_shf[c]));
      }
    }
#pragma unroll
    for (int q = 0; q < WF4; q++) {
      int f = tid + q * 256;
      int k = f / (BC / 4), cq = f % (BC / 4);
      *(float4*)&wsh[k * BC + cq * 4] =
          *(const float4*)(W + (size_t)(kb + k) * BC + cq * 4);
    }
    __syncthreads();
#pragma unroll
    for (int kk = 0; kk < 32; kk++) {
      float av[4];
#pragma unroll
      for (int r = 0; r < 4; r++) av[r] = xs[(ty * 4 + r) * 33 + kk];
#pragma unroll
      for (int j = 0; j < NJ; j++) {
        float bv = wsh[kk * BC + tx + j * 16];
#pragma unroll
        for (int r = 0; r < 4; r++) acc[r][j] = fmaf(av[r], bv, acc[r][j]);
      }
    }
  }
#pragma unroll
  for (int r = 0; r < 4; r++) {
    int row = r0 + ty * 4 + r;
    float dr = dis[row];
#pragma unroll
    for (int j = 0; j < NJ; j++)
      out[(size_t)row * BC + tx + j * 16] = __float2bfloat16(acc[r][j] * dr);
  }
}

// ---------------------------------------------------------------- aggregation
__global__ __launch_bounds__(256) void agg1_kernel(const unsigned short* __restrict__ hs,
    const int* __restrict__ csr_src, const int* __restrict__ offsets,
    const int* __restrict__ counts, const float* __restrict__ dis,
    unsigned short* __restrict__ t1) {
  int tid = threadIdx.x;
  int wv = tid >> 6, lane = tid & 63;
  int d = blockIdx.x * 4 + wv;
  int g = lane >> 4, l = lane & 15;
  float dd = dis[d];
  float acc[8];
  if (g == 0) {
    short8v v = *(const short8v*)(hs + (size_t)d * 128 + l * 8);
#pragma unroll
    for (int j = 0; j < 8; j++) acc[j] = bf2f((unsigned short)v[j]) * dd;
  } else {
#pragma unroll
    for (int j = 0; j < 8; j++) acc[j] = 0.f;
  }
  int s0 = offsets[d], n = counts[d];
  int i = g;
  for (; i + 4 < n; i += 8) {
    int sa = csr_src[s0 + i];
    int sb = csr_src[s0 + i + 4];
    float da = dis[sa], db = dis[sb];
    short8v va = *(const short8v*)(hs + (size_t)sa * 128 + l * 8);
    short8v vb = *(const short8v*)(hs + (size_t)sb * 128 + l * 8);
#pragma unroll
    for (int j = 0; j < 8; j++) acc[j] = fmaf(bf2f((unsigned short)va[j]), da, acc[j]);
#pragma unroll
    for (int j = 0; j < 8; j++) acc[j] = fmaf(bf2f((unsigned short)vb[j]), db, acc[j]);
  }
  if (i < n) {
    int sa = csr_src[s0 + i];
    float da = dis[sa];
    short8v va = *(const short8v*)(hs + (size_t)sa * 128 + l * 8);
#pragma unroll
    for (int j = 0; j < 8; j++) acc[j] = fmaf(bf2f((unsigned short)va[j]), da, acc[j]);
  }
#pragma unroll
  for (int j = 0; j < 8; j++) {
    acc[j] += __shfl_xor(acc[j], 16, 64);
    acc[j] += __shfl_xor(acc[j], 32, 64);
  }
  if (g == 0) {
    short8v o;
#pragma unroll
    for (int j = 0; j < 8; j++) o[j] = (short)f2bf(acc[j] * dd);
    *(short8v*)(t1 + (size_t)d * 128 + l * 8) = o;
  }
}

__global__ __launch_bounds__(256) void agg2_kernel(const unsigned short* __restrict__ hs,
    const int* __restrict__ csr_src, const int* __restrict__ offsets,
    const int* __restrict__ counts, const float* __restrict__ dis,
    float* __restrict__ t2) {
  int tid = threadIdx.x;
  int wv = tid >> 6, lane = tid & 63;
  int d = blockIdx.x * 4 + wv;
  int g = lane >> 3, l = lane & 7;
  float acc[8];
  if (g == 0) {
    short8v v = *(const short8v*)(hs + (size_t)d * 64 + l * 8);
#pragma unroll
    for (int j = 0; j < 8; j++) acc[j] = bf2f((unsigned short)v[j]);
  } else {
#pragma unroll
    for (int j = 0; j < 8; j++) acc[j] = 0.f;
  }
  int s0 = offsets[d], n = counts[d];
  int i = g;
  for (; i + 8 < n; i += 16) {
    int sa = csr_src[s0 + i];
    int sb = csr_src[s0 + i + 8];
    short8v va = *(const short8v*)(hs + (size_t)sa * 64 + l * 8);
    short8v vb = *(const short8v*)(hs + (size_t)sb * 64 + l * 8);
#pragma unroll
    for (int j = 0; j < 8; j++) acc[j] += bf2f((unsigned short)va[j]);
#pragma unroll
    for (int j = 0; j < 8; j++) acc[j] += bf2f((unsigned short)vb[j]);
  }
  if (i < n) {
    int sa = csr_src[s0 + i];
    short8v va = *(const short8v*)(hs + (size_t)sa * 64 + l * 8);
#pragma unroll
    for (int j = 0; j < 8; j++) acc[j] += bf2f((unsigned short)va[j]);
  }
#pragma unroll
  for (int j = 0; j < 8; j++) {
    acc[j] += __shfl_xor(acc[j], 8, 64);
    acc[j] += __shfl_xor(acc[j], 16, 64);
    acc[j] += __shfl_xor(acc[j], 32, 64);
  }
  if (g == 0) {
    float dd = dis[d];
    float* o = t2 + (size_t)d * 64 + l * 8;
    f32x4 o0 = {acc[0] * dd, acc[1] * dd, acc[2] * dd, acc[3] * dd};
    f32x4 o1 = {acc[4] * dd, acc[5] * dd, acc[6] * dd, acc[7] * dd};
    *(f32x4*)o = o0;
    *(f32x4*)(o + 4) = o1;
  }
}

// ---------------------------------------------------------------- BN stats
template <int C, bool BF16>
__global__ __launch_bounds__(256) void stats_kernel(const void* __restrict__ t,
                                                    float* __restrict__ sums) {
  constexpr int RP = 256 / C;
  int c = threadIdx.x % C;
  int rr = threadIdx.x / C;
  float s = 0.f, s2 = 0.f;
  for (int r = blockIdx.x * RP + rr; r < kN; r += gridDim.x * RP) {
    float v;
    if constexpr (BF16) v = bf2f(((const unsigned short*)t)[(size_t)r * C + c]);
    else v = ((const float*)t)[(size_t)r * C + c];
    s += v;
    s2 += v * v;
  }
  atomicAdd(&sums[c], s);
  atomicAdd(&sums[C + c], s2);
}

// ---------------------------------------------------------------- z + heads (fused)
__global__ __launch_bounds__(256) void zheads_kernel(const float* __restrict__ t2,
    const float* __restrict__ sums, const float* __restrict__ gg,
    const float* __restrict__ bb2,
    const float* __restrict__ wbin, const float* __restrict__ bbin,
    const float* __restrict__ wmc, const float* __restrict__ bmc,
    const float* __restrict__ wcont, const float* __restrict__ bcont,
    float* __restrict__ out0, unsigned short* __restrict__ zb) {
  __shared__ float wT[30 * 64];
  __shared__ float bias[32];
  __shared__ float s_scl[64], s_shf[64];
  int tid = threadIdx.x;
  for (int idx = tid; idx < 1920; idx += 256) {
    int j = idx >> 6, k = idx & 63;
    const float* src = (j < 10) ? wbin : (j < 20) ? wmc : wcont;
    wT[idx] = src[k * 10 + (j % 10)];
  }
  if (tid < 30)
    bias[tid] = (tid < 10) ? bbin[tid] : (tid < 20) ? bmc[tid - 10] : bcont[tid - 20];
  if (tid < 64) {
    float mean = sums[tid] / (float)kN;
    float var = sums[64 + tid] / (float)kN - mean * mean;
    float inv = rsqrtf(var + kEps);
    float sc = gg[tid] * inv;
    s_scl[tid] = sc;
    s_shf[tid] = bb2[tid] - mean * sc;
  }
  __syncthreads();
  int n = blockIdx.x * 256 + tid;
  float zr[64];
  const float4* t4 = (const float4*)(t2 + (size_t)n * 64);
#pragma unroll
  for (int q = 0; q < 16; q++) {
    float4 v = t4[q];
    zr[4 * q + 0] = fmaxf(0.f, fmaf(v.x, s_scl[4 * q + 0], s_shf[4 * q + 0]));
    zr[4 * q + 1] = fmaxf(0.f, fmaf(v.y, s_scl[4 * q + 1], s_shf[4 * q + 1]));
    zr[4 * q + 2] = fmaxf(0.f, fmaf(v.z, s_scl[4 * q + 2], s_shf[4 * q + 2]));
    zr[4 * q + 3] = fmaxf(0.f, fmaf(v.w, s_scl[4 * q + 3], s_shf[4 * q + 3]));
  }
  unsigned short* zrow = zb + (size_t)n * 64;
#pragma unroll
  for (int q = 0; q < 8; q++) {
    short8v o;
#pragma unroll
    for (int j = 0; j < 8; j++) o[j] = (short)f2bf(zr[q * 8 + j]);
    *(short8v*)(zrow + q * 8) = o;
  }
  float acc[30];
#pragma unroll
  for (int j = 0; j < 30; j++) {
    float s = bias[j];
#pragma unroll
    for (int kc = 0; kc < 16; kc++) {
      f32x4 wv = *(const f32x4*)&wT[j * 64 + kc * 4];
      s = fmaf(zr[4 * kc + 0], wv.x, s);
      s = fmaf(zr[4 * kc + 1], wv.y, s);
      s = fmaf(zr[4 * kc + 2], wv.z, s);
      s = fmaf(zr[4 * kc + 3], wv.w, s);
    }
    acc[j] = s;
  }
  float* o = out0 + (size_t)n * 30;
#pragma unroll
  for (int j = 0; j < 10; j++) o[j] = 1.f / (1.f + expf(-acc[j]));
  float m1 = fmaxf(fmaxf(acc[10], acc[11]), fmaxf(acc[12], acc[13]));
  float e1[4], s1 = 0.f;
#pragma unroll
  for (int j = 0; j < 4; j++) { e1[j] = expf(acc[10 + j] - m1); s1 += e1[j]; }
#pragma unroll
  for (int j = 0; j < 4; j++) o[10 + j] = e1[j] / s1;
  float m2 = acc[14];
#pragma unroll
  for (int j = 15; j < 20; j++) m2 = fmaxf(m2, acc[j]);
  float e2[6], s2 = 0.f;
#pragma unroll
  for (int j = 0; j < 6; j++) { e2[j] = expf(acc[14 + j] - m2); s2 += e2[j]; }
#pragma unroll
  for (int j = 0; j < 6; j++) o[14 + j] = e2[j] / s2;
#pragma unroll
  for (int j = 0; j < 10; j++) o[20 + j] = acc[20 + j];
}

// ---------------------------------------------------------------- adj + edge (fused, heterogeneous blocks)
// blocks [0,1024): edge path. blocks [1024,1024+16384): adj 128x128 tile,
// write-out staged in TWO 64-row chunks (LDS 33.8 KB); launch_bounds(256,3)
// -> 3 blocks/CU (12 waves) for +50% write-issue duty cycle vs R9's 2.
__global__ __launch_bounds__(256, 3) void adjedge_kernel(const short* __restrict__ zb,
    const int* __restrict__ srcs, const int* __restrict__ dsts,
    const short* __restrict__ wfr, const float* __restrict__ be,
    float* __restrict__ adj, float* __restrict__ eout) {
  __shared__ float cs[64 * 132];
  int tid = threadIdx.x;
  int wid = tid >> 6, lane = tid & 63;
  int lr = lane & 15, lg = lane >> 4;

  if (blockIdx.x < 1024) {
    // ---------------- edge path ----------------
    float* es = &cs[wid * 256];
    int gw = blockIdx.x * 4 + wid;       // 4096 waves total
    short8v bfr[4];
#pragma unroll
    for (int f = 0; f < 4; f++)
      bfr[f] = *(const short8v*)(wfr + ((size_t)f * 64 + lane) * 8);
    float bias = be[lr];
    for (int t = 0; t < 8; t++) {
      int e0 = (gw * 8 + t) * 16;
      int se = srcs[e0 + lr], de = dsts[e0 + lr];
      short8v a0 = *(const short8v*)(zb + (size_t)se * 64 + lg * 8);
      short8v a1 = *(const short8v*)(zb + (size_t)se * 64 + 32 + lg * 8);
      short8v a2 = *(const short8v*)(zb + (size_t)de * 64 + lg * 8);
      short8v a3 = *(const short8v*)(zb + (size_t)de * 64 + 32 + lg * 8);
      f32x4 acc = {0.f, 0.f, 0.f, 0.f};
      acc = __builtin_amdgcn_mfma_f32_16x16x32_bf16(a0, bfr[0], acc, 0, 0, 0);
      acc = __builtin_amdgcn_mfma_f32_16x16x32_bf16(a1, bfr[1], acc, 0, 0, 0);
      acc = __builtin_amdgcn_mfma_f32_16x16x32_bf16(a2, bfr[2], acc, 0, 0, 0);
      acc = __builtin_amdgcn_mfma_f32_16x16x32_bf16(a3, bfr[3], acc, 0, 0, 0);
#pragma unroll
      for (int r = 0; r < 4; r++)
        es[(lg * 4 + r) * 16 + lr] = acc[r] + bias;
      f32x4 v = *(const f32x4*)&es[lane * 4];
      *(f32x4*)(eout + (size_t)e0 * 16 + lane * 4) = v;
    }
    return;
  }

  // ---------------- adj path (bcol-fast; 2-chunk LDS write-out) ----------------
  int bid = blockIdx.x - 1024;
  int bcol = bid & 127;
  int brow = bid >> 7;
  int half = wid >> 1;                  // 0: rows 0-63, 1: rows 64-127
  int lj0 = (wid & 1) * 64;
  int i0 = brow * 128 + half * 64;
  int j0 = bcol * 128 + lj0;
  short8v a[4][2], b[4][2];
#pragma unroll
  for (int mt = 0; mt < 4; mt++)
#pragma unroll
    for (int ks = 0; ks < 2; ks++)
      a[mt][ks] = *(const short8v*)(zb + (size_t)(i0 + mt * 16 + lr) * 64 + ks * 32 + lg * 8);
#pragma unroll
  for (int nt = 0; nt < 4; nt++)
#pragma unroll
    for (int ks = 0; ks < 2; ks++)
      b[nt][ks] = *(const short8v*)(zb + (size_t)(j0 + nt * 16 + lr) * 64 + ks * 32 + lg * 8);
  f32x4 acc[4][4];
#pragma unroll
  for (int mt = 0; mt < 4; mt++)
#pragma unroll
    for (int nt = 0; nt < 4; nt++) {
      f32x4 zz = {0.f, 0.f, 0.f, 0.f};
      acc[mt][nt] = zz;
    }
#pragma unroll
  for (int ks = 0; ks < 2; ks++)
#pragma unroll
    for (int mt = 0; mt < 4; mt++)
#pragma unroll
      for (int nt = 0; nt < 4; nt++)
        acc[mt][nt] = __builtin_amdgcn_mfma_f32_16x16x32_bf16(a[mt][ks], b[nt][ks],
                                                              acc[mt][nt], 0, 0, 0);
  // Two chunks of 64 rows. Chunk c is produced by waves with half==c
  // (their local rows are mt*16+lg*4+r in [0,64)), consumed by all threads.
#pragma unroll
  for (int c = 0; c < 2; c++) {
    if (c) __syncthreads();             // previous chunk's readers done
    if (half == c) {
#pragma unroll
      for (int mt = 0; mt < 4; mt++)
#pragma unroll
        for (int nt = 0; nt < 4; nt++)
#pragma unroll
          for (int r = 0; r < 4; r++)
            cs[(mt * 16 + lg * 4 + r) * 132 + lj0 + nt * 16 + lr] = acc[mt][nt][r];
    }
    __syncthreads();
    // copy out 64 rows x 128 cols = 2048 float4; 8 per thread
    size_t gb = (size_t)(brow * 128 + c * 64) * kN + bcol * 128;
#pragma unroll
    for (int q = 0; q < 8; q++) {
      int idx = q * 256 + tid;
      int row = idx >> 5, c4 = idx & 31;
      f32x4 v = *(const f32x4*)&cs[row * 132 + c4 * 4];
      *(f32x4*)(adj + gb + (size_t)row * kN + c4 * 4) = v;
    }
  }
}

// ---------------------------------------------------------------- launch
extern "C" void kernel_launch(void* const* d_in, const int* in_sizes, int n_in,
                              void* d_out, int out_size, void* d_ws, size_t ws_size,
                              hipStream_t stream) {
  const float* x      = (const float*)d_in[0];
  const int*   ei     = (const int*)d_in[1];
  const float* w1     = (const float*)d_in[3];
  const float* bn1_g  = (const float*)d_in[5];
  const float* bn1_b  = (const float*)d_in[6];
  const float* w2     = (const float*)d_in[7];
  const float* bn2_g  = (const float*)d_in[9];
  const float* bn2_b  = (const float*)d_in[10];
  const float* w_bin  = (const float*)d_in[11];
  const float* b_bin  = (const float*)d_in[12];
  const float* w_mc   = (const float*)d_in[13];
  const float* b_mc   = (const float*)d_in[14];
  const float* w_cont = (const float*)d_in[15];
  const float* b_cont = (const float*)d_in[16];
  const float* w_edge = (const float*)d_in[17];
  const float* b_edge = (const float*)d_in[18];

  float* out0 = (float*)d_out;
  float* adj  = out0 + (size_t)kN * 30;
  float* eout = adj + (size_t)kN * kN;

  char* wp = (char*)d_ws;
  auto alloc = [&](size_t bytes) {
    char* p = wp;
    wp += (bytes + 255) & ~(size_t)255;
    return p;
  };
  int*   counts  = (int*)alloc((size_t)kN * 4);
  int*   offsets = (int*)alloc((size_t)kN * 4);
  int*   pos     = (int*)alloc((size_t)kN * 4);
  int*   csr_src = (int*)alloc((size_t)kE * 4);
  float* dis     = (float*)alloc((size_t)kN * 4);
  float* sums1   = (float*)alloc(256 * 4);
  float* sums2   = (float*)alloc(128 * 4);
  unsigned short* hs1 = (unsigned short*)alloc((size_t)kN * 128 * 2);
  unsigned short* t1  = (unsigned short*)alloc((size_t)kN * 128 * 2);
  unsigned short* hs2 = (unsigned short*)alloc((size_t)kN * 64 * 2);
  float* t2      = (float*)alloc((size_t)kN * 64 * 4);
  unsigned short* zb  = (unsigned short*)alloc((size_t)kN * 64 * 2);
  __hip_bfloat16* wfr = (__hip_bfloat16*)alloc(2048 * 2);

  const int* esrc = ei;
  const int* edst = ei + kE;

  zero_kernel<<<dim3(64), dim3(256), 0, stream>>>(counts, sums1, sums2, w_edge, wfr);
  histgemm1_kernel<<<dim3(2048 + 256), dim3(256), 0, stream>>>(
      edst, counts, x, w1, (__hip_bfloat16*)hs1);
  scan_kernel<<<dim3(1), dim3(1024), 0, stream>>>(counts, offsets, pos, dis);
  fill_kernel<<<dim3(2048), dim3(256), 0, stream>>>(esrc, edst, pos, csr_src);

  agg1_kernel<<<dim3(kN / 4), dim3(256), 0, stream>>>(
      hs1, csr_src, offsets, counts, dis, t1);
  stats_kernel<128, true><<<dim3(256), dim3(256), 0, stream>>>(t1, sums1);

  gemm2_kernel<<<dim3(kN / 64), dim3(256), 0, stream>>>(
      t1, w2, sums1, bn1_g, bn1_b, dis, (__hip_bfloat16*)hs2);
  agg2_kernel<<<dim3(kN / 4), dim3(256), 0, stream>>>(
      hs2, csr_src, offsets, counts, dis, t2);
  stats_kernel<64, false><<<dim3(256), dim3(256), 0, stream>>>(t2, sums2);

  zheads_kernel<<<dim3(kN / 256), dim3(256), 0, stream>>>(
      t2, sums2, bn2_g, bn2_b, w_bin, b_bin, w_mc, b_mc, w_cont, b_cont, out0, zb);

  adjedge_kernel<<<dim3(1024 + 16384), dim3(256), 0, stream>>>(
      (const short*)zb, esrc, edst, (const short*)wfr, b_edge, adj, eout);
}